// Round 1
// baseline (971.569 us; speedup 1.0000x reference)
//
#include <hip/hip_runtime.h>
#include <hip/hip_bf16.h>

// VQ-VAE encoder/decoder pipeline, fp32 end-to-end.
// B=16, C0=8, T0=32768 -> conv(8->64,k7,s2,p3)+relu -> [16,64,16384]
// -> conv(64->128,k5,s2,p2)+relu -> [16,128,8192]
// -> conv(128->64,k3,s2,p1) = z_e [16,64,4096]
// -> VQ vs codebook[512,64] -> z_q, losses
// -> convT(64->128)+relu -> convT(128->64)+relu -> convT(64->8) -> recon loss
// Outputs: conditioning [16,64] (mean_t z_q), vq_loss, commitment_loss, recon_loss.

#define NB 16
#define T0 32768
#define T1 16384
#define T2 8192
#define T3 4096
#define NCODES 512
#define EDIM 64

__device__ __forceinline__ float block_sum256(float v) {
    #pragma unroll
    for (int off = 32; off > 0; off >>= 1) v += __shfl_down(v, off, 64);
    __shared__ float red[4];
    int lane = threadIdx.x & 63, wv = threadIdx.x >> 6;
    if (lane == 0) red[wv] = v;
    __syncthreads();
    return red[0] + red[1] + red[2] + red[3];
}

// ---------------- forward conv (stride 2), register-blocked over OCT ocs ----
template<int IC, int K, int PAD, int OC, int OCT, bool RELU>
__global__ __launch_bounds__(256)
void conv_fwd(const float* __restrict__ x, const float* __restrict__ w,
              const float* __restrict__ bias, float* __restrict__ y,
              int Tin, int Tout) {
    int t   = blockIdx.x * 256 + threadIdx.x;
    int ocg = blockIdx.y * OCT;
    int b   = blockIdx.z;
    const float* xb = x + (size_t)b * IC * Tin;
    float acc[OCT];
    #pragma unroll
    for (int j = 0; j < OCT; j++) acc[j] = bias[ocg + j];
    int p0 = 2 * t - PAD;
    for (int ic = 0; ic < IC; ic++) {
        const float* xr = xb + (size_t)ic * Tin;
        float xw[K];
        #pragma unroll
        for (int k = 0; k < K; k++) {
            int p = p0 + k;
            xw[k] = ((unsigned)p < (unsigned)Tin) ? xr[p] : 0.f;
        }
        #pragma unroll
        for (int j = 0; j < OCT; j++) {
            const float* wr = w + ((size_t)(ocg + j) * IC + ic) * K;  // uniform -> s_load
            #pragma unroll
            for (int k = 0; k < K; k++) acc[j] += xw[k] * wr[k];
        }
    }
    float* yb = y + ((size_t)b * OC + ocg) * Tout + t;
    #pragma unroll
    for (int j = 0; j < OCT; j++) {
        float v = acc[j];
        if (RELU) v = fmaxf(v, 0.f);
        yb[(size_t)j * Tout] = v;
    }
}

// ------------- conv-transpose (k4,s2,p1): even/odd output pair per thread ---
// y[2m]   = sum_ic x[m]*w[k1] + x[m-1]*w[k3]
// y[2m+1] = sum_ic x[m+1]*w[k0] + x[m]*w[k2]
template<int IC, int OC, int OCT, bool RELU>
__global__ __launch_bounds__(256)
void conv_t(const float* __restrict__ x, const float* __restrict__ w,
            const float* __restrict__ bias, float* __restrict__ y, int Tin) {
    int m   = blockIdx.x * 256 + threadIdx.x;
    int ocg = blockIdx.y * OCT;
    int b   = blockIdx.z;
    const float* xb = x + (size_t)b * IC * Tin;
    float ae[OCT], ao[OCT];
    #pragma unroll
    for (int j = 0; j < OCT; j++) { ae[j] = bias[ocg + j]; ao[j] = ae[j]; }
    for (int ic = 0; ic < IC; ic++) {
        const float* xr = xb + (size_t)ic * Tin;
        float x0  = xr[m];
        float xm1 = (m > 0) ? xr[m - 1] : 0.f;
        float xp1 = (m + 1 < Tin) ? xr[m + 1] : 0.f;
        #pragma unroll
        for (int j = 0; j < OCT; j++) {
            const float* wr = w + ((size_t)ic * OC + ocg + j) * 4;  // uniform -> s_load
            ae[j] += x0 * wr[1] + xm1 * wr[3];
            ao[j] += xp1 * wr[0] + x0 * wr[2];
        }
    }
    int Tout = 2 * Tin;
    float* yb = y + ((size_t)b * OC + ocg) * Tout + 2 * m;
    #pragma unroll
    for (int j = 0; j < OCT; j++) {
        float ve = ae[j], vo = ao[j];
        if (RELU) { ve = fmaxf(ve, 0.f); vo = fmaxf(vo, 0.f); }
        yb[(size_t)j * Tout]     = ve;
        yb[(size_t)j * Tout + 1] = vo;
    }
}

// ---- final conv-transpose (64->8) fused with recon MSE; x_recon never stored
__global__ __launch_bounds__(256)
void convt3_loss(const float* __restrict__ r2, const float* __restrict__ w,
                 const float* __restrict__ bias, const float* __restrict__ x,
                 float* __restrict__ acc) {
    const int IC = 64, OC = 8, Tin = T1;
    int m = blockIdx.x * 256 + threadIdx.x;
    int b = blockIdx.z;
    const float* xb = r2 + (size_t)b * IC * Tin;
    float ae[OC], ao[OC];
    #pragma unroll
    for (int j = 0; j < OC; j++) { ae[j] = bias[j]; ao[j] = ae[j]; }
    for (int ic = 0; ic < IC; ic++) {
        const float* xr = xb + (size_t)ic * Tin;
        float x0  = xr[m];
        float xm1 = (m > 0) ? xr[m - 1] : 0.f;
        float xp1 = (m + 1 < Tin) ? xr[m + 1] : 0.f;
        #pragma unroll
        for (int j = 0; j < OC; j++) {
            const float* wr = w + ((size_t)ic * OC + j) * 4;
            ae[j] += x0 * wr[1] + xm1 * wr[3];
            ao[j] += xp1 * wr[0] + x0 * wr[2];
        }
    }
    float s = 0.f;
    const float* xin = x + (size_t)b * OC * T0;
    #pragma unroll
    for (int j = 0; j < OC; j++) {
        float de = ae[j] - xin[(size_t)j * T0 + 2 * m];
        float d1 = ao[j] - xin[(size_t)j * T0 + 2 * m + 1];
        s += de * de + d1 * d1;
    }
    s = block_sum256(s);
    if (threadIdx.x == 0) atomicAdd(acc + 1, s);
}

// -------- prep: codebook squared norms + zero the loss accumulators ---------
__global__ void prep_kernel(const float* __restrict__ cb, float* __restrict__ c2,
                            float* __restrict__ acc) {
    int c = threadIdx.x;  // 512 threads
    if (c < 8) acc[c] = 0.f;
    float s = 0.f;
    #pragma unroll
    for (int d = 0; d < EDIM; d++) { float v = cb[c * EDIM + d]; s += v * v; }
    c2[c] = s;
}

// -------- VQ: per-thread z vector in regs, codebook streamed via scalar pipe
__global__ __launch_bounds__(256)
void quant_kernel(const float* __restrict__ ze, const float* __restrict__ cb,
                  const float* __restrict__ c2, float* __restrict__ zq,
                  float* __restrict__ acc) {
    int v = blockIdx.x * 256 + threadIdx.x;  // 65536 vectors
    int b = v >> 12;
    int t = v & (T3 - 1);
    const float* zb = ze + (size_t)b * EDIM * T3 + t;
    float z[EDIM];
    #pragma unroll
    for (int d = 0; d < EDIM; d++) z[d] = zb[(size_t)d * T3];
    float best = 3.4e38f;
    int bi = 0;
    for (int c = 0; c < NCODES; c++) {
        const float* cr = cb + c * EDIM;  // uniform -> s_load
        float dot = 0.f;
        #pragma unroll
        for (int d = 0; d < EDIM; d++) dot += z[d] * cr[d];
        float s = c2[c] - 2.f * dot;
        if (s < best) { best = s; bi = c; }  // strict <: first-index argmin
    }
    float vql = 0.f;
    const float* cv = cb + (size_t)bi * EDIM;
    float* zqb = zq + (size_t)b * EDIM * T3 + t;
    #pragma unroll
    for (int d = 0; d < EDIM; d++) {
        float q = cv[d];
        zqb[(size_t)d * T3] = q;
        float df = z[d] - q;
        vql += df * df;
    }
    vql = block_sum256(vql);
    if (threadIdx.x == 0) atomicAdd(acc, vql);
}

// -------- conditioning: mean over t of z_q, one block per (b,d) row ---------
__global__ __launch_bounds__(256)
void cond_kernel(const float* __restrict__ zq, float* __restrict__ out) {
    int row = blockIdx.x;  // b*64+d, 1024 rows
    const float* zr = zq + (size_t)row * T3;
    float s = 0.f;
    for (int t = threadIdx.x; t < T3; t += 256) s += zr[t];
    s = block_sum256(s);
    if (threadIdx.x == 0) out[row] = s * (1.f / (float)T3);
}

__global__ void fin_kernel(const float* __restrict__ acc, float* __restrict__ out) {
    if (threadIdx.x == 0) {
        float vq = acc[0] * (1.f / 4194304.f);  // B*D*T3
        out[1024] = vq;   // vq_loss
        out[1025] = vq;   // commitment_loss (identical value)
        out[1026] = acc[1] * (1.f / 4194304.f);  // B*C0*T0
    }
}

extern "C" void kernel_launch(void* const* d_in, const int* in_sizes, int n_in,
                              void* d_out, int out_size, void* d_ws, size_t ws_size,
                              hipStream_t stream) {
    const float* x   = (const float*)d_in[0];
    const float* w1  = (const float*)d_in[1];
    const float* b1  = (const float*)d_in[2];
    const float* w2  = (const float*)d_in[3];
    const float* b2  = (const float*)d_in[4];
    const float* w3  = (const float*)d_in[5];
    const float* b3  = (const float*)d_in[6];
    const float* cb  = (const float*)d_in[7];
    const float* dw1 = (const float*)d_in[8];
    const float* db1 = (const float*)d_in[9];
    const float* dw2 = (const float*)d_in[10];
    const float* db2 = (const float*)d_in[11];
    const float* dw3 = (const float*)d_in[12];
    const float* db3 = (const float*)d_in[13];
    float* out = (float*)d_out;

    float* ws = (float*)d_ws;
    float* a1  = ws;                     // [16,64,16384] conv1 out; later r2
    float* a2  = ws + 16777216;          // [16,128,8192] conv2 out; later r1
    float* ze  = ws + 33554432;          // [16,64,4096]
    float* zq  = ws + 37748736;          // [16,64,4096]
    float* c2  = ws + 41943040;          // [512]
    float* acc = ws + 41943552;          // [8]

    prep_kernel<<<1, 512, 0, stream>>>(cb, c2, acc);
    conv_fwd<8, 7, 3, 64, 8, true><<<dim3(T1 / 256, 8, NB), 256, 0, stream>>>(
        x, w1, b1, a1, T0, T1);
    conv_fwd<64, 5, 2, 128, 16, true><<<dim3(T2 / 256, 8, NB), 256, 0, stream>>>(
        a1, w2, b2, a2, T1, T2);
    conv_fwd<128, 3, 1, 64, 16, false><<<dim3(T3 / 256, 4, NB), 256, 0, stream>>>(
        a2, w3, b3, ze, T2, T3);
    quant_kernel<<<65536 / 256, 256, 0, stream>>>(ze, cb, c2, zq, acc);
    cond_kernel<<<NB * EDIM, 256, 0, stream>>>(zq, out);
    conv_t<64, 128, 16, true><<<dim3(T3 / 256, 8, NB), 256, 0, stream>>>(
        zq, dw1, db1, a2, T3);                    // r1 overwrites a2
    conv_t<128, 64, 16, true><<<dim3(T2 / 256, 4, NB), 256, 0, stream>>>(
        a2, dw2, db2, a1, T2);                    // r2 overwrites a1
    convt3_loss<<<dim3(T1 / 256, 1, NB), 256, 0, stream>>>(a1, dw3, db3, x, acc);
    fin_kernel<<<1, 64, 0, stream>>>(acc, out);
}

// Round 2
// 937.537 us; speedup vs baseline: 1.0363x; 1.0363x over previous
//
#include <hip/hip_runtime.h>
#include <hip/hip_bf16.h>

// VQ-VAE encoder/decoder pipeline, fp32 end-to-end.
// Round 2: (a) quant_kernel __launch_bounds__(256,4) so z[64] stays in VGPRs
// (round-1 showed VGPR_Count=44 -> z spilled to scratch, 260us, VALUBusy 24%);
// (b) all convs time-tiled TT outputs/thread (strided by 256 so loads stay
// coalesced) so each wave-uniform weight s_load round feeds TT x more FMAs.

#define NB 16
#define T0 32768
#define T1 16384
#define T2 8192
#define T3 4096
#define NCODES 512
#define EDIM 64

__device__ __forceinline__ float block_sum256(float v) {
    #pragma unroll
    for (int off = 32; off > 0; off >>= 1) v += __shfl_down(v, off, 64);
    __shared__ float red[4];
    int lane = threadIdx.x & 63, wv = threadIdx.x >> 6;
    if (lane == 0) red[wv] = v;
    __syncthreads();
    return red[0] + red[1] + red[2] + red[3];
}

// ---------------- forward conv (stride 2), OCT ocs x TT time-points --------
template<int IC, int K, int PAD, int OC, int OCT, int TT, bool RELU>
__global__ __launch_bounds__(256, 4)
void conv_fwd(const float* __restrict__ x, const float* __restrict__ w,
              const float* __restrict__ bias, float* __restrict__ y,
              int Tin, int Tout) {
    int t0  = blockIdx.x * (256 * TT) + threadIdx.x;
    int ocg = blockIdx.y * OCT;
    int b   = blockIdx.z;
    const float* xb = x + (size_t)b * IC * Tin;
    float acc[OCT][TT];
    #pragma unroll
    for (int j = 0; j < OCT; j++) {
        float bj = bias[ocg + j];
        #pragma unroll
        for (int i = 0; i < TT; i++) acc[j][i] = bj;
    }
    for (int ic = 0; ic < IC; ic++) {
        const float* xr = xb + (size_t)ic * Tin;
        float xw[TT][K];
        #pragma unroll
        for (int i = 0; i < TT; i++) {
            int p0 = 2 * (t0 + i * 256) - PAD;
            #pragma unroll
            for (int k = 0; k < K; k++) {
                int p = p0 + k;
                xw[i][k] = ((unsigned)p < (unsigned)Tin) ? xr[p] : 0.f;
            }
        }
        #pragma unroll
        for (int j = 0; j < OCT; j++) {
            const float* wr = w + ((size_t)(ocg + j) * IC + ic) * K;  // uniform -> s_load
            float wk[K];
            #pragma unroll
            for (int k = 0; k < K; k++) wk[k] = wr[k];
            #pragma unroll
            for (int i = 0; i < TT; i++)
                #pragma unroll
                for (int k = 0; k < K; k++)
                    acc[j][i] = fmaf(xw[i][k], wk[k], acc[j][i]);
        }
    }
    float* yb = y + ((size_t)b * OC + ocg) * Tout + t0;
    #pragma unroll
    for (int j = 0; j < OCT; j++)
        #pragma unroll
        for (int i = 0; i < TT; i++) {
            float v = acc[j][i];
            if (RELU) v = fmaxf(v, 0.f);
            yb[(size_t)j * Tout + i * 256] = v;
        }
}

// ------------- conv-transpose (k4,s2,p1): even/odd pair x TT per thread ----
// y[2m]   = sum_ic x[m]*w[k1] + x[m-1]*w[k3]
// y[2m+1] = sum_ic x[m+1]*w[k0] + x[m]*w[k2]
template<int IC, int OC, int OCT, int TT, bool RELU>
__global__ __launch_bounds__(256, 4)
void conv_t(const float* __restrict__ x, const float* __restrict__ w,
            const float* __restrict__ bias, float* __restrict__ y, int Tin) {
    int m0  = blockIdx.x * (256 * TT) + threadIdx.x;
    int ocg = blockIdx.y * OCT;
    int b   = blockIdx.z;
    const float* xb = x + (size_t)b * IC * Tin;
    float ae[OCT][TT], ao[OCT][TT];
    #pragma unroll
    for (int j = 0; j < OCT; j++) {
        float bj = bias[ocg + j];
        #pragma unroll
        for (int i = 0; i < TT; i++) { ae[j][i] = bj; ao[j][i] = bj; }
    }
    for (int ic = 0; ic < IC; ic++) {
        const float* xr = xb + (size_t)ic * Tin;
        float x0[TT], xm1[TT], xp1[TT];
        #pragma unroll
        for (int i = 0; i < TT; i++) {
            int m = m0 + i * 256;
            x0[i]  = xr[m];
            xm1[i] = (m > 0) ? xr[m - 1] : 0.f;
            xp1[i] = (m + 1 < Tin) ? xr[m + 1] : 0.f;
        }
        #pragma unroll
        for (int j = 0; j < OCT; j++) {
            const float* wr = w + ((size_t)ic * OC + ocg + j) * 4;  // uniform -> s_load
            float w0 = wr[0], w1 = wr[1], w2 = wr[2], w3 = wr[3];
            #pragma unroll
            for (int i = 0; i < TT; i++) {
                ae[j][i] = fmaf(x0[i], w1, fmaf(xm1[i], w3, ae[j][i]));
                ao[j][i] = fmaf(xp1[i], w0, fmaf(x0[i], w2, ao[j][i]));
            }
        }
    }
    int Tout = 2 * Tin;
    float* yb = y + ((size_t)b * OC + ocg) * Tout + 2 * m0;
    #pragma unroll
    for (int j = 0; j < OCT; j++)
        #pragma unroll
        for (int i = 0; i < TT; i++) {
            float ve = ae[j][i], vo = ao[j][i];
            if (RELU) { ve = fmaxf(ve, 0.f); vo = fmaxf(vo, 0.f); }
            yb[(size_t)j * Tout + i * 512]     = ve;
            yb[(size_t)j * Tout + i * 512 + 1] = vo;
        }
}

// ---- final conv-transpose (64->8) fused with recon MSE; x_recon never stored
__global__ __launch_bounds__(256, 4)
void convt3_loss(const float* __restrict__ r2, const float* __restrict__ w,
                 const float* __restrict__ bias, const float* __restrict__ x,
                 float* __restrict__ acc) {
    const int IC = 64, OC = 8, Tin = T1, TT = 2;
    int m0 = blockIdx.x * (256 * TT) + threadIdx.x;
    int b  = blockIdx.z;
    const float* xb = r2 + (size_t)b * IC * Tin;
    float ae[OC][TT], ao[OC][TT];
    #pragma unroll
    for (int j = 0; j < OC; j++) {
        float bj = bias[j];
        #pragma unroll
        for (int i = 0; i < TT; i++) { ae[j][i] = bj; ao[j][i] = bj; }
    }
    for (int ic = 0; ic < IC; ic++) {
        const float* xr = xb + (size_t)ic * Tin;
        float x0[TT], xm1[TT], xp1[TT];
        #pragma unroll
        for (int i = 0; i < TT; i++) {
            int m = m0 + i * 256;
            x0[i]  = xr[m];
            xm1[i] = (m > 0) ? xr[m - 1] : 0.f;
            xp1[i] = (m + 1 < Tin) ? xr[m + 1] : 0.f;
        }
        #pragma unroll
        for (int j = 0; j < OC; j++) {
            const float* wr = w + ((size_t)ic * OC + j) * 4;
            float w0 = wr[0], w1 = wr[1], w2 = wr[2], w3 = wr[3];
            #pragma unroll
            for (int i = 0; i < TT; i++) {
                ae[j][i] = fmaf(x0[i], w1, fmaf(xm1[i], w3, ae[j][i]));
                ao[j][i] = fmaf(xp1[i], w0, fmaf(x0[i], w2, ao[j][i]));
            }
        }
    }
    float s = 0.f;
    const float* xin = x + (size_t)b * OC * T0;
    #pragma unroll
    for (int j = 0; j < OC; j++)
        #pragma unroll
        for (int i = 0; i < TT; i++) {
            int t = 2 * (m0 + i * 256);
            float de = ae[j][i] - xin[(size_t)j * T0 + t];
            float d1 = ao[j][i] - xin[(size_t)j * T0 + t + 1];
            s += de * de + d1 * d1;
        }
    s = block_sum256(s);
    if (threadIdx.x == 0) atomicAdd(acc + 1, s);
}

// -------- prep: codebook squared norms + zero the loss accumulators ---------
__global__ void prep_kernel(const float* __restrict__ cb, float* __restrict__ c2,
                            float* __restrict__ acc) {
    int c = threadIdx.x;  // 512 threads
    if (c < 8) acc[c] = 0.f;
    float s = 0.f;
    #pragma unroll
    for (int d = 0; d < EDIM; d++) { float v = cb[c * EDIM + d]; s += v * v; }
    c2[c] = s;
}

// -------- VQ: per-thread z vector in regs, codebook streamed via scalar pipe
// (256,4): 128-VGPR budget so z[64] is NOT spilled (round-1: 44 VGPR = spill).
__global__ __launch_bounds__(256, 4)
void quant_kernel(const float* __restrict__ ze, const float* __restrict__ cb,
                  const float* __restrict__ c2, float* __restrict__ zq,
                  float* __restrict__ acc) {
    int v = blockIdx.x * 256 + threadIdx.x;  // 65536 vectors
    int b = v >> 12;
    int t = v & (T3 - 1);
    const float* zb = ze + (size_t)b * EDIM * T3 + t;
    float z[EDIM];
    #pragma unroll
    for (int d = 0; d < EDIM; d++) z[d] = zb[(size_t)d * T3];
    float best = 3.4e38f;
    int bi = 0;
    for (int c = 0; c < NCODES; c++) {
        const float* cr = cb + c * EDIM;  // uniform -> s_load
        float dot = 0.f;
        #pragma unroll
        for (int d = 0; d < EDIM; d++) dot = fmaf(z[d], cr[d], dot);
        float s = c2[c] - 2.f * dot;
        if (s < best) { best = s; bi = c; }  // strict <: first-index argmin
    }
    float vql = 0.f;
    const float* cv = cb + (size_t)bi * EDIM;
    float* zqb = zq + (size_t)b * EDIM * T3 + t;
    #pragma unroll
    for (int d = 0; d < EDIM; d++) {
        float q = cv[d];
        zqb[(size_t)d * T3] = q;
        float df = z[d] - q;
        vql += df * df;
    }
    vql = block_sum256(vql);
    if (threadIdx.x == 0) atomicAdd(acc, vql);
}

// -------- conditioning: mean over t of z_q, one block per (b,d) row ---------
__global__ __launch_bounds__(256)
void cond_kernel(const float* __restrict__ zq, float* __restrict__ out) {
    int row = blockIdx.x;  // b*64+d, 1024 rows
    const float* zr = zq + (size_t)row * T3;
    float s = 0.f;
    for (int t = threadIdx.x; t < T3; t += 256) s += zr[t];
    s = block_sum256(s);
    if (threadIdx.x == 0) out[row] = s * (1.f / (float)T3);
}

__global__ void fin_kernel(const float* __restrict__ acc, float* __restrict__ out) {
    if (threadIdx.x == 0) {
        float vq = acc[0] * (1.f / 4194304.f);  // B*D*T3
        out[1024] = vq;   // vq_loss
        out[1025] = vq;   // commitment_loss (identical value)
        out[1026] = acc[1] * (1.f / 4194304.f);  // B*C0*T0
    }
}

extern "C" void kernel_launch(void* const* d_in, const int* in_sizes, int n_in,
                              void* d_out, int out_size, void* d_ws, size_t ws_size,
                              hipStream_t stream) {
    const float* x   = (const float*)d_in[0];
    const float* w1  = (const float*)d_in[1];
    const float* b1  = (const float*)d_in[2];
    const float* w2  = (const float*)d_in[3];
    const float* b2  = (const float*)d_in[4];
    const float* w3  = (const float*)d_in[5];
    const float* b3  = (const float*)d_in[6];
    const float* cb  = (const float*)d_in[7];
    const float* dw1 = (const float*)d_in[8];
    const float* db1 = (const float*)d_in[9];
    const float* dw2 = (const float*)d_in[10];
    const float* db2 = (const float*)d_in[11];
    const float* dw3 = (const float*)d_in[12];
    const float* db3 = (const float*)d_in[13];
    float* out = (float*)d_out;

    float* ws = (float*)d_ws;
    float* a1  = ws;                     // [16,64,16384] conv1 out; later r2
    float* a2  = ws + 16777216;          // [16,128,8192] conv2 out; later r1
    float* ze  = ws + 33554432;          // [16,64,4096]
    float* zq  = ws + 37748736;          // [16,64,4096]
    float* c2  = ws + 41943040;          // [512]
    float* acc = ws + 41943552;          // [8]

    prep_kernel<<<1, 512, 0, stream>>>(cb, c2, acc);
    // conv1: 8->64, k7, TT=4: grid (16,8,16)
    conv_fwd<8, 7, 3, 64, 8, 4, true><<<dim3(T1 / 1024, 8, NB), 256, 0, stream>>>(
        x, w1, b1, a1, T0, T1);
    // conv2: 64->128, k5, TT=4: grid (8,8,16)
    conv_fwd<64, 5, 2, 128, 16, 4, true><<<dim3(T2 / 1024, 8, NB), 256, 0, stream>>>(
        a1, w2, b2, a2, T1, T2);
    // conv3: 128->64, k3, TT=2: grid (8,4,16)
    conv_fwd<128, 3, 1, 64, 16, 2, false><<<dim3(T3 / 512, 4, NB), 256, 0, stream>>>(
        a2, w3, b3, ze, T2, T3);
    quant_kernel<<<65536 / 256, 256, 0, stream>>>(ze, cb, c2, zq, acc);
    cond_kernel<<<NB * EDIM, 256, 0, stream>>>(zq, out);
    // convT1: 64->128, TT=2: grid (8,8,16)
    conv_t<64, 128, 16, 2, true><<<dim3(T3 / 512, 8, NB), 256, 0, stream>>>(
        zq, dw1, db1, a2, T3);                    // r1 overwrites a2
    // convT2: 128->64, TT=2: grid (16,4,16)
    conv_t<128, 64, 16, 2, true><<<dim3(T2 / 512, 4, NB), 256, 0, stream>>>(
        a2, dw2, db2, a1, T2);                    // r2 overwrites a1
    // convT3 fused with recon loss, TT=2: grid (32,1,16)
    convt3_loss<<<dim3(T1 / 512, 1, NB), 256, 0, stream>>>(a1, dw3, db3, x, acc);
    fin_kernel<<<1, 64, 0, stream>>>(acc, out);
}

// Round 3
// 703.037 us; speedup vs baseline: 1.3820x; 1.3336x over previous
//
#include <hip/hip_runtime.h>
#include <hip/hip_bf16.h>

// VQ-VAE pipeline, fp32. Round 3:
// (a) quant rewritten as LDS-tiled GEMM + fused argmin (round-2 showed the
//     compiler re-reads z from L2 every code iter: 8.6 TB -> 253us predicted,
//     260us measured). New: 128t x 128c x 64d tiles, 8x8 micro-tile/thread.
// (b) convs stage per-block weight slice in LDS (broadcast ds_read) instead
//     of per-ic s_load chains that serialize on SGPR pressure.

#define NB 16
#define T0 32768
#define T1 16384
#define T2 8192
#define T3 4096
#define NCODES 512
#define EDIM 64

__device__ __forceinline__ float block_sum256(float v) {
    #pragma unroll
    for (int off = 32; off > 0; off >>= 1) v += __shfl_down(v, off, 64);
    __shared__ float red[4];
    int lane = threadIdx.x & 63, wv = threadIdx.x >> 6;
    if (lane == 0) red[wv] = v;
    __syncthreads();
    return red[0] + red[1] + red[2] + red[3];
}

// ---------------- forward conv (stride 2), weights in LDS -------------------
template<int IC, int K, int PAD, int OC, int OCT, int TT, bool RELU>
__global__ __launch_bounds__(256, 3)
void conv_fwd(const float* __restrict__ x, const float* __restrict__ w,
              const float* __restrict__ bias, float* __restrict__ y,
              int Tin, int Tout) {
    constexpr int KP = (K + 3) & ~3;            // pad row to float4 alignment
    __shared__ float wl[IC * OCT * KP];
    int tid = threadIdx.x;
    int ocg = blockIdx.y * OCT;
    // stage weights: global [oc][ic][k] -> lds [ic][oc_local][k]
    for (int idx = tid; idx < IC * OCT * K; idx += 256) {
        int j = idx / (IC * K);
        int r = idx - j * (IC * K);             // r = ic*K + k
        int ic = r / K, k = r - ic * K;
        wl[(ic * OCT + j) * KP + k] = w[(size_t)(ocg + j) * IC * K + r];
    }
    __syncthreads();

    int t0 = blockIdx.x * (256 * TT) + tid;
    int b  = blockIdx.z;
    const float* xb = x + (size_t)b * IC * Tin;
    float acc[OCT][TT];
    #pragma unroll
    for (int j = 0; j < OCT; j++) {
        float bj = bias[ocg + j];
        #pragma unroll
        for (int i = 0; i < TT; i++) acc[j][i] = bj;
    }
    for (int ic = 0; ic < IC; ic++) {
        const float* xr = xb + (size_t)ic * Tin;
        float xw[TT][K];
        #pragma unroll
        for (int i = 0; i < TT; i++) {
            int p0 = 2 * (t0 + i * 256) - PAD;
            #pragma unroll
            for (int k = 0; k < K; k++) {
                int p = p0 + k;
                xw[i][k] = ((unsigned)p < (unsigned)Tin) ? xr[p] : 0.f;
            }
        }
        #pragma unroll
        for (int j = 0; j < OCT; j++) {
            const float* wr = wl + (ic * OCT + j) * KP;
            float wk[K];
            #pragma unroll
            for (int k = 0; k < K; k++) wk[k] = wr[k];   // contiguous, aligned
            #pragma unroll
            for (int i = 0; i < TT; i++)
                #pragma unroll
                for (int k = 0; k < K; k++)
                    acc[j][i] = fmaf(xw[i][k], wk[k], acc[j][i]);
        }
    }
    float* yb = y + ((size_t)b * OC + ocg) * Tout + t0;
    #pragma unroll
    for (int j = 0; j < OCT; j++)
        #pragma unroll
        for (int i = 0; i < TT; i++) {
            float v = acc[j][i];
            if (RELU) v = fmaxf(v, 0.f);
            yb[(size_t)j * Tout + i * 256] = v;
        }
}

// ------------- conv-transpose (k4,s2,p1), weights in LDS --------------------
// y[2m]   = sum_ic x[m]*w[k1] + x[m-1]*w[k3]
// y[2m+1] = sum_ic x[m+1]*w[k0] + x[m]*w[k2]
template<int IC, int OC, int OCT, int TT, bool RELU>
__global__ __launch_bounds__(256, 3)
void conv_t(const float* __restrict__ x, const float* __restrict__ w,
            const float* __restrict__ bias, float* __restrict__ y, int Tin) {
    __shared__ float wl[IC * OCT * 4];
    int tid = threadIdx.x;
    int ocg = blockIdx.y * OCT;
    // global [ic][oc][4] float4 -> lds [ic][oc_local][4]
    for (int idx = tid; idx < IC * OCT; idx += 256) {
        int ic = idx / OCT, j = idx - ic * OCT;
        ((float4*)wl)[idx] = ((const float4*)w)[(size_t)ic * OC + ocg + j];
    }
    __syncthreads();

    int m0 = blockIdx.x * (256 * TT) + tid;
    int b  = blockIdx.z;
    const float* xb = x + (size_t)b * IC * Tin;
    float ae[OCT][TT], ao[OCT][TT];
    #pragma unroll
    for (int j = 0; j < OCT; j++) {
        float bj = bias[ocg + j];
        #pragma unroll
        for (int i = 0; i < TT; i++) { ae[j][i] = bj; ao[j][i] = bj; }
    }
    for (int ic = 0; ic < IC; ic++) {
        const float* xr = xb + (size_t)ic * Tin;
        float x0[TT], xm1[TT], xp1[TT];
        #pragma unroll
        for (int i = 0; i < TT; i++) {
            int m = m0 + i * 256;
            x0[i]  = xr[m];
            xm1[i] = (m > 0) ? xr[m - 1] : 0.f;
            xp1[i] = (m + 1 < Tin) ? xr[m + 1] : 0.f;
        }
        #pragma unroll
        for (int j = 0; j < OCT; j++) {
            float4 wv = ((const float4*)wl)[ic * OCT + j];
            #pragma unroll
            for (int i = 0; i < TT; i++) {
                ae[j][i] = fmaf(x0[i], wv.y, fmaf(xm1[i], wv.w, ae[j][i]));
                ao[j][i] = fmaf(xp1[i], wv.x, fmaf(x0[i], wv.z, ao[j][i]));
            }
        }
    }
    int Tout = 2 * Tin;
    float* yb = y + ((size_t)b * OC + ocg) * Tout + 2 * m0;
    #pragma unroll
    for (int j = 0; j < OCT; j++)
        #pragma unroll
        for (int i = 0; i < TT; i++) {
            float ve = ae[j][i], vo = ao[j][i];
            if (RELU) { ve = fmaxf(ve, 0.f); vo = fmaxf(vo, 0.f); }
            yb[(size_t)j * Tout + i * 512]     = ve;
            yb[(size_t)j * Tout + i * 512 + 1] = vo;
        }
}

// ---- final conv-transpose (64->8) fused with recon MSE ---------------------
__global__ __launch_bounds__(256, 3)
void convt3_loss(const float* __restrict__ r2, const float* __restrict__ w,
                 const float* __restrict__ bias, const float* __restrict__ x,
                 float* __restrict__ acc) {
    const int IC = 64, OC = 8, Tin = T1, TT = 2;
    __shared__ float wl[IC * OC * 4];
    int tid = threadIdx.x;
    for (int idx = tid; idx < IC * OC; idx += 256)
        ((float4*)wl)[idx] = ((const float4*)w)[idx];
    __syncthreads();

    int m0 = blockIdx.x * (256 * TT) + tid;
    int b  = blockIdx.z;
    const float* xb = r2 + (size_t)b * IC * Tin;
    float ae[OC][TT], ao[OC][TT];
    #pragma unroll
    for (int j = 0; j < OC; j++) {
        float bj = bias[j];
        #pragma unroll
        for (int i = 0; i < TT; i++) { ae[j][i] = bj; ao[j][i] = bj; }
    }
    for (int ic = 0; ic < IC; ic++) {
        const float* xr = xb + (size_t)ic * Tin;
        float x0[TT], xm1[TT], xp1[TT];
        #pragma unroll
        for (int i = 0; i < TT; i++) {
            int m = m0 + i * 256;
            x0[i]  = xr[m];
            xm1[i] = (m > 0) ? xr[m - 1] : 0.f;
            xp1[i] = (m + 1 < Tin) ? xr[m + 1] : 0.f;
        }
        #pragma unroll
        for (int j = 0; j < OC; j++) {
            float4 wv = ((const float4*)wl)[ic * OC + j];
            #pragma unroll
            for (int i = 0; i < TT; i++) {
                ae[j][i] = fmaf(x0[i], wv.y, fmaf(xm1[i], wv.w, ae[j][i]));
                ao[j][i] = fmaf(xp1[i], wv.x, fmaf(x0[i], wv.z, ao[j][i]));
            }
        }
    }
    float s = 0.f;
    const float* xin = x + (size_t)b * OC * T0;
    #pragma unroll
    for (int j = 0; j < OC; j++)
        #pragma unroll
        for (int i = 0; i < TT; i++) {
            int t = 2 * (m0 + i * 256);
            float de = ae[j][i] - xin[(size_t)j * T0 + t];
            float d1 = ao[j][i] - xin[(size_t)j * T0 + t + 1];
            s += de * de + d1 * d1;
        }
    s = block_sum256(s);
    if (threadIdx.x == 0) atomicAdd(acc + 1, s);
}

// -------- prep: codebook squared norms + zero the loss accumulators ---------
__global__ void prep_kernel(const float* __restrict__ cb, float* __restrict__ c2,
                            float* __restrict__ acc) {
    int c = threadIdx.x;  // 512 threads
    if (c < 8) acc[c] = 0.f;
    float s = 0.f;
    #pragma unroll
    for (int d = 0; d < EDIM; d++) { float v = cb[c * EDIM + d]; s += v * v; }
    c2[c] = s;
}

// -------- VQ as tiled GEMM + fused argmin -----------------------------------
// Block: 128 t (all 64 dims in LDS) x code-chunks of 128 (transposed in LDS).
// Thread micro-tile: 8 t x 8 codes; score = |c|^2 - 2*dot.
#define MT 128
#define NCH 128
__global__ __launch_bounds__(256, 2)
void quant_kernel(const float* __restrict__ ze, const float* __restrict__ cb,
                  const float* __restrict__ c2g, float* __restrict__ zq,
                  float* __restrict__ acc) {
    __shared__ float lA[64 * 132];   // [d][t], stride 132 breaks write conflicts
    __shared__ float lB[64 * NCH];   // [d][c]
    __shared__ int   ibuf[MT];
    int tid = threadIdx.x;
    int bb = blockIdx.x >> 5;            // 32 tiles per batch (4096/128)
    int t0 = (blockIdx.x & 31) * MT;
    // stage A: ze[bb][d][t0..t0+127]
    {
        int d  = tid >> 2;
        int tb = (tid & 3) * 32;
        const float4* src = (const float4*)(ze + ((size_t)bb * EDIM + d) * T3 + t0 + tb);
        float4* dst = (float4*)(lA + d * 132 + tb);
        #pragma unroll
        for (int q = 0; q < 8; ++q) dst[q] = src[q];
    }
    int tx = tid & 15, ty = tid >> 4;    // 16x16 thread grid
    float best[8];
    int   bidx[8];
    #pragma unroll
    for (int i = 0; i < 8; ++i) { best[i] = 3.4e38f; bidx[i] = 0; }

    for (int cc = 0; cc < NCODES / NCH; ++cc) {
        __syncthreads();                 // lB reuse fence (also covers lA stage)
        {   // stage B chunk transposed: cb[cc*128+c][d] -> lB[d][c]
            int c  = tid >> 1;
            int db = (tid & 1) * 32;
            const float4* src = (const float4*)(cb + ((size_t)(cc * NCH) + c) * EDIM + db);
            #pragma unroll
            for (int q = 0; q < 8; ++q) {
                float4 v = src[q];
                int d = db + q * 4;
                lB[(d + 0) * NCH + c] = v.x;
                lB[(d + 1) * NCH + c] = v.y;
                lB[(d + 2) * NCH + c] = v.z;
                lB[(d + 3) * NCH + c] = v.w;
            }
        }
        __syncthreads();
        float dot[8][8];
        #pragma unroll
        for (int i = 0; i < 8; ++i)
            #pragma unroll
            for (int j = 0; j < 8; ++j) dot[i][j] = 0.f;
        for (int d = 0; d < 64; ++d) {
            float4 a0 = *(const float4*)(lA + d * 132 + ty * 8);
            float4 a1 = *(const float4*)(lA + d * 132 + ty * 8 + 4);
            float4 b0 = *(const float4*)(lB + d * NCH + tx * 8);
            float4 b1 = *(const float4*)(lB + d * NCH + tx * 8 + 4);
            float av[8] = {a0.x, a0.y, a0.z, a0.w, a1.x, a1.y, a1.z, a1.w};
            float bv[8] = {b0.x, b0.y, b0.z, b0.w, b1.x, b1.y, b1.z, b1.w};
            #pragma unroll
            for (int i = 0; i < 8; ++i)
                #pragma unroll
                for (int j = 0; j < 8; ++j)
                    dot[i][j] = fmaf(av[i], bv[j], dot[i][j]);
        }
        float4 u0 = *(const float4*)(c2g + cc * NCH + tx * 8);
        float4 u1 = *(const float4*)(c2g + cc * NCH + tx * 8 + 4);
        float c2v[8] = {u0.x, u0.y, u0.z, u0.w, u1.x, u1.y, u1.z, u1.w};
        #pragma unroll
        for (int j = 0; j < 8; ++j) {   // ascending code index: first-min wins
            int cidx = cc * NCH + tx * 8 + j;
            #pragma unroll
            for (int i = 0; i < 8; ++i) {
                float s = c2v[j] - 2.f * dot[i][j];
                if (s < best[i]) { best[i] = s; bidx[i] = cidx; }
            }
        }
    }
    // reduce argmin across the 16 tx lanes sharing each t-row
    #pragma unroll
    for (int i = 0; i < 8; ++i) {
        float bsc = best[i];
        int   bix = bidx[i];
        #pragma unroll
        for (int m = 1; m < 16; m <<= 1) {
            float ob = __shfl_xor(bsc, m, 64);
            int   oi = __shfl_xor(bix, m, 64);
            if (ob < bsc || (ob == bsc && oi < bix)) { bsc = ob; bix = oi; }
        }
        if (tx == 0) ibuf[ty * 8 + i] = bix;
    }
    __syncthreads();
    // write z_q (coalesced in t) + vq-loss partial
    int tl = tid & (MT - 1);
    int dh = (tid >> 7) * 32;            // two d-halves
    int code = ibuf[tl];
    const float4* cv = (const float4*)(cb + (size_t)code * EDIM + dh);
    float* zqb = zq + ((size_t)bb * EDIM + dh) * T3 + t0 + tl;
    float vql = 0.f;
    #pragma unroll
    for (int q = 0; q < 8; ++q) {
        float4 v = cv[q];
        float qq[4] = {v.x, v.y, v.z, v.w};
        #pragma unroll
        for (int l = 0; l < 4; ++l) {
            int d = q * 4 + l;
            float zv = lA[(dh + d) * 132 + tl];
            float df = zv - qq[l];
            vql += df * df;
            zqb[(size_t)d * T3] = qq[l];
        }
    }
    vql = block_sum256(vql);
    if (tid == 0) atomicAdd(acc, vql);
}

// -------- conditioning: mean over t of z_q, one block per (b,d) row ---------
__global__ __launch_bounds__(256)
void cond_kernel(const float* __restrict__ zq, float* __restrict__ out) {
    int row = blockIdx.x;  // b*64+d, 1024 rows
    const float* zr = zq + (size_t)row * T3;
    float s = 0.f;
    for (int t = threadIdx.x; t < T3; t += 256) s += zr[t];
    s = block_sum256(s);
    if (threadIdx.x == 0) out[row] = s * (1.f / (float)T3);
}

__global__ void fin_kernel(const float* __restrict__ acc, float* __restrict__ out) {
    if (threadIdx.x == 0) {
        float vq = acc[0] * (1.f / 4194304.f);  // B*D*T3
        out[1024] = vq;   // vq_loss
        out[1025] = vq;   // commitment_loss (identical value)
        out[1026] = acc[1] * (1.f / 4194304.f);  // B*C0*T0
    }
}

extern "C" void kernel_launch(void* const* d_in, const int* in_sizes, int n_in,
                              void* d_out, int out_size, void* d_ws, size_t ws_size,
                              hipStream_t stream) {
    const float* x   = (const float*)d_in[0];
    const float* w1  = (const float*)d_in[1];
    const float* b1  = (const float*)d_in[2];
    const float* w2  = (const float*)d_in[3];
    const float* b2  = (const float*)d_in[4];
    const float* w3  = (const float*)d_in[5];
    const float* b3  = (const float*)d_in[6];
    const float* cb  = (const float*)d_in[7];
    const float* dw1 = (const float*)d_in[8];
    const float* db1 = (const float*)d_in[9];
    const float* dw2 = (const float*)d_in[10];
    const float* db2 = (const float*)d_in[11];
    const float* dw3 = (const float*)d_in[12];
    const float* db3 = (const float*)d_in[13];
    float* out = (float*)d_out;

    float* ws = (float*)d_ws;
    float* a1  = ws;                     // [16,64,16384] conv1 out; later r2
    float* a2  = ws + 16777216;          // [16,128,8192] conv2 out; later r1
    float* ze  = ws + 33554432;          // [16,64,4096]
    float* zq  = ws + 37748736;          // [16,64,4096]
    float* c2  = ws + 41943040;          // [512]
    float* acc = ws + 41943552;          // [8]

    prep_kernel<<<1, 512, 0, stream>>>(cb, c2, acc);
    // conv1: 8->64, k7, OCT=8, TT=4
    conv_fwd<8, 7, 3, 64, 8, 4, true><<<dim3(T1 / 1024, 8, NB), 256, 0, stream>>>(
        x, w1, b1, a1, T0, T1);
    // conv2: 64->128, k5, OCT=16, TT=4
    conv_fwd<64, 5, 2, 128, 16, 4, true><<<dim3(T2 / 1024, 8, NB), 256, 0, stream>>>(
        a1, w2, b2, a2, T1, T2);
    // conv3: 128->64, k3, OCT=16, TT=2
    conv_fwd<128, 3, 1, 64, 16, 2, false><<<dim3(T3 / 512, 4, NB), 256, 0, stream>>>(
        a2, w3, b3, ze, T2, T3);
    quant_kernel<<<NB * (T3 / MT), 256, 0, stream>>>(ze, cb, c2, zq, acc);
    cond_kernel<<<NB * EDIM, 256, 0, stream>>>(zq, out);
    // convT1: 64->128, OCT=16, TT=2
    conv_t<64, 128, 16, 2, true><<<dim3(T3 / 512, 8, NB), 256, 0, stream>>>(
        zq, dw1, db1, a2, T3);                    // r1 overwrites a2
    // convT2: 128->64, OCT=16, TT=2
    conv_t<128, 64, 16, 2, true><<<dim3(T2 / 512, 4, NB), 256, 0, stream>>>(
        a2, dw2, db2, a1, T2);                    // r2 overwrites a1
    // convT3 fused with recon loss, TT=2
    convt3_loss<<<dim3(T1 / 512, 1, NB), 256, 0, stream>>>(a1, dw3, db3, x, acc);
    fin_kernel<<<1, 64, 0, stream>>>(acc, out);
}

// Round 4
// 354.365 us; speedup vs baseline: 2.7417x; 1.9839x over previous
//
#include <hip/hip_runtime.h>
#include <hip/hip_bf16.h>

// VQ-VAE pipeline. Round 4: bf16 MFMA for the 4 big convs (round-3: conv2
// alone 198us fp32-VALU-bound; VALU floor for conv stack ~190us -> matrix
// pipe is the only way down). Activations channels-last bf16 [b][t][c];
// x-tiles in LDS with XOR swizzle (c8 ^= (row>>1)) so A-frags are single
// conflict-free ds_read_b128; weights pre-transposed to [tap][oc][ic] bf16
// read as B-frags straight from global (L2-resident). conv1/convt3/quant
// stay fp32 VALU. z_e fp32 for exact-ish losses; z_q bf16 feeds decoder.

#define NB 16
#define T0 32768
#define T1 16384
#define T2 8192
#define T3 4096
#define NCODES 512
#define EDIM 64

typedef __attribute__((ext_vector_type(8)))  short short8;
typedef __attribute__((ext_vector_type(16))) float f32x16;

__device__ __forceinline__ float b2f(short s) {
    unsigned u = ((unsigned)(unsigned short)s) << 16;
    float f; __builtin_memcpy(&f, &u, 4); return f;
}
__device__ __forceinline__ short f2bs(float f) {
    __hip_bfloat16 h = __float2bfloat16(f);
    short s; __builtin_memcpy(&s, &h, 2); return s;
}

__device__ __forceinline__ float block_sum256(float v) {
    #pragma unroll
    for (int off = 32; off > 0; off >>= 1) v += __shfl_down(v, off, 64);
    __shared__ float red[4];
    int lane = threadIdx.x & 63, wv = threadIdx.x >> 6;
    if (lane == 0) red[wv] = v;
    __syncthreads();
    return red[0] + red[1] + red[2] + red[3];
}

// ---------------- conv1: fp32 VALU, 8ch in, 64ch out, k7 s2 p3 --------------
// out bf16 channels-last [b][T1][64]; OCT=16 per blockIdx.y, TT=2
__global__ __launch_bounds__(256)
void conv1_kernel(const float* __restrict__ x, const float* __restrict__ w1,
                  const float* __restrict__ b1, short* __restrict__ y) {
    __shared__ float wt[8 * 7 * 16];   // [(ic*7+k)*16 + j]
    __shared__ float bl[16];
    int tid = threadIdx.x;
    int ocg = blockIdx.y;              // 4 groups of 16 oc
    for (int idx = tid; idx < 896; idx += 256) {
        int j = idx & 15, r = idx >> 4;
        int ic = r / 7, k = r - ic * 7;
        wt[idx] = w1[((size_t)(ocg * 16 + j) * 8 + ic) * 7 + k];
    }
    if (tid < 16) bl[tid] = b1[ocg * 16 + tid];
    __syncthreads();

    int t0 = blockIdx.x * 512 + tid;
    int b  = blockIdx.z;
    float acc[2][16];
    #pragma unroll
    for (int i = 0; i < 2; i++)
        #pragma unroll
        for (int j = 0; j < 16; j++) acc[i][j] = 0.f;
    for (int ic = 0; ic < 8; ic++) {
        const float* xr = x + ((size_t)b * 8 + ic) * T0;
        float xw[2][7];
        #pragma unroll
        for (int i = 0; i < 2; i++) {
            int p0 = 2 * (t0 + i * 256) - 3;
            #pragma unroll
            for (int k = 0; k < 7; k++) {
                int p = p0 + k;
                xw[i][k] = ((unsigned)p < (unsigned)T0) ? xr[p] : 0.f;
            }
        }
        #pragma unroll
        for (int k = 0; k < 7; k++) {
            const float4* w4 = (const float4*)(wt + (ic * 7 + k) * 16);
            #pragma unroll
            for (int j4 = 0; j4 < 4; j4++) {
                float4 wv = w4[j4];
                #pragma unroll
                for (int i = 0; i < 2; i++) {
                    acc[i][j4 * 4 + 0] = fmaf(xw[i][k], wv.x, acc[i][j4 * 4 + 0]);
                    acc[i][j4 * 4 + 1] = fmaf(xw[i][k], wv.y, acc[i][j4 * 4 + 1]);
                    acc[i][j4 * 4 + 2] = fmaf(xw[i][k], wv.z, acc[i][j4 * 4 + 2]);
                    acc[i][j4 * 4 + 3] = fmaf(xw[i][k], wv.w, acc[i][j4 * 4 + 3]);
                }
            }
        }
    }
    #pragma unroll
    for (int i = 0; i < 2; i++) {
        int t = t0 + i * 256;
        short8 s0, s1;
        #pragma unroll
        for (int j = 0; j < 8; j++) {
            float v0 = fmaxf(acc[i][j] + bl[j], 0.f);
            float v1 = fmaxf(acc[i][j + 8] + bl[j + 8], 0.f);
            s0[j] = f2bs(v0); s1[j] = f2bs(v1);
        }
        short* yp = y + ((size_t)b * T1 + t) * 64 + ocg * 16;
        *(short8*)(yp)     = s0;
        *(short8*)(yp + 8) = s1;
    }
}

// --------- MFMA forward conv: stride 2, channels-last bf16 ------------------
// x [b][Tin][IC] bf16; wb [TAPS][OC][IC] bf16; y [b][Tout][OC]
template<int IC, int OC, int TAPS, int PAD, int BT, int NW, bool RELU, bool F32OUT>
__global__ __launch_bounds__(NW * 64, 2)
void conv_mfma_fwd(const short* __restrict__ x, const short* __restrict__ wb,
                   const float* __restrict__ bias, void* __restrict__ yout,
                   int Tin, int Tout) {
    constexpr int C8 = IC / 8;
    constexpr int NR = 2 * (BT - 1) + TAPS;
    __shared__ short lx[NR * IC];
    const int tid = threadIdx.x;
    const int b   = blockIdx.z;
    const int t0  = blockIdx.x * BT;
    const int r0  = 2 * t0 - PAD;
    const short* xg = x + (size_t)b * Tin * IC;
    short8 zz = {0, 0, 0, 0, 0, 0, 0, 0};
    for (int idx = tid; idx < NR * C8; idx += NW * 64) {
        int row = idx / C8, c8 = idx - row * C8;
        int gr = r0 + row;
        short8 v = zz;
        if ((unsigned)gr < (unsigned)Tin)
            v = *(const short8*)(xg + (size_t)gr * IC + c8 * 8);
        int sw = c8 ^ ((row >> 1) & (C8 - 1));
        *(short8*)(lx + row * IC + sw * 8) = v;
    }
    __syncthreads();

    const int wv = tid >> 6, lane = tid & 63;
    const int tl = wv * 32;            // wave's t-offset (BT = NW*32)
    const int lm = lane & 31, lk = lane >> 5;
    f32x16 acc[OC / 32];
    #pragma unroll
    for (int oj = 0; oj < OC / 32; oj++)
        #pragma unroll
        for (int r = 0; r < 16; r++) acc[oj][r] = 0.f;

    #pragma unroll
    for (int tap = 0; tap < TAPS; tap++) {
        #pragma unroll
        for (int kc = 0; kc < IC / 16; kc++) {
            int row = 2 * (tl + lm) + tap;
            int c8  = kc * 2 + lk;
            int sw  = c8 ^ ((row >> 1) & (C8 - 1));
            short8 a = *(const short8*)(lx + row * IC + sw * 8);
            const short* wg = wb + ((size_t)tap * OC + lm) * IC + kc * 16 + lk * 8;
            #pragma unroll
            for (int oj = 0; oj < OC / 32; oj++) {
                short8 bf = *(const short8*)(wg + (size_t)oj * 32 * IC);
                acc[oj] = __builtin_amdgcn_mfma_f32_32x32x16_bf16(a, bf, acc[oj], 0, 0, 0);
            }
        }
    }
    // epilogue: D row=(r&3)+8*(r>>2)+4*lk (t), col=lm (oc)
    #pragma unroll
    for (int oj = 0; oj < OC / 32; oj++) {
        int oc = oj * 32 + lm;
        float bs = bias[oc];
        #pragma unroll
        for (int r = 0; r < 16; r++) {
            int t = t0 + tl + (r & 3) + 8 * (r >> 2) + 4 * lk;
            float v = acc[oj][r] + bs;
            if (RELU) v = fmaxf(v, 0.f);
            if (F32OUT)
                ((float*)yout)[((size_t)b * Tout + t) * OC + oc] = v;
            else
                ((short*)yout)[((size_t)b * Tout + t) * OC + oc] = f2bs(v);
        }
    }
}

// --------- MFMA conv-transpose (k4 s2 p1), both parities --------------------
// x [b][Tin][IC] bf16; wb [4][OC][IC] bf16; y [b][2*Tin][OC] bf16
// y[2m]   = x[m]*W1 + x[m-1]*W3 ;  y[2m+1] = x[m+1]*W0 + x[m]*W2
template<int IC, int OC, int BT, int NW, bool RELU>
__global__ __launch_bounds__(NW * 64, 2)
void conv_mfma_t(const short* __restrict__ x, const short* __restrict__ wb,
                 const float* __restrict__ bias, short* __restrict__ y, int Tin) {
    constexpr int C8 = IC / 8;
    constexpr int NR = BT + 2;
    __shared__ short lx[NR * IC];
    const int tid = threadIdx.x;
    const int b   = blockIdx.z;
    const int m0  = blockIdx.x * BT;
    const int r0  = m0 - 1;
    const short* xg = x + (size_t)b * Tin * IC;
    short8 zz = {0, 0, 0, 0, 0, 0, 0, 0};
    for (int idx = tid; idx < NR * C8; idx += NW * 64) {
        int row = idx / C8, c8 = idx - row * C8;
        int gr = r0 + row;
        short8 v = zz;
        if ((unsigned)gr < (unsigned)Tin)
            v = *(const short8*)(xg + (size_t)gr * IC + c8 * 8);
        int sw = c8 ^ ((row >> 1) & (C8 - 1));
        *(short8*)(lx + row * IC + sw * 8) = v;
    }
    __syncthreads();

    const int wv = tid >> 6, lane = tid & 63;
    const int ml = wv * 32;
    const int lm = lane & 31, lk = lane >> 5;
    f32x16 accE[OC / 32], accO[OC / 32];
    #pragma unroll
    for (int oj = 0; oj < OC / 32; oj++)
        #pragma unroll
        for (int r = 0; r < 16; r++) { accE[oj][r] = 0.f; accO[oj][r] = 0.f; }

    #pragma unroll
    for (int kc = 0; kc < IC / 16; kc++) {
        int c8 = kc * 2 + lk;
        int rA = (ml + lm);            // local rows: m-1 -> rA, m -> rA+1, m+1 -> rA+2
        short8 a_m1, a_0, a_p1;
        {
            int row = rA;
            a_m1 = *(const short8*)(lx + row * IC + (c8 ^ ((row >> 1) & (C8 - 1))) * 8);
            row = rA + 1;
            a_0  = *(const short8*)(lx + row * IC + (c8 ^ ((row >> 1) & (C8 - 1))) * 8);
            row = rA + 2;
            a_p1 = *(const short8*)(lx + row * IC + (c8 ^ ((row >> 1) & (C8 - 1))) * 8);
        }
        const short* wg = wb + (size_t)lm * IC + kc * 16 + lk * 8;
        #pragma unroll
        for (int oj = 0; oj < OC / 32; oj++) {
            const short* wo = wg + (size_t)oj * 32 * IC;
            short8 w0 = *(const short8*)(wo);
            short8 w1 = *(const short8*)(wo + (size_t)1 * OC * IC);
            short8 w2 = *(const short8*)(wo + (size_t)2 * OC * IC);
            short8 w3 = *(const short8*)(wo + (size_t)3 * OC * IC);
            accE[oj] = __builtin_amdgcn_mfma_f32_32x32x16_bf16(a_0,  w1, accE[oj], 0, 0, 0);
            accE[oj] = __builtin_amdgcn_mfma_f32_32x32x16_bf16(a_m1, w3, accE[oj], 0, 0, 0);
            accO[oj] = __builtin_amdgcn_mfma_f32_32x32x16_bf16(a_p1, w0, accO[oj], 0, 0, 0);
            accO[oj] = __builtin_amdgcn_mfma_f32_32x32x16_bf16(a_0,  w2, accO[oj], 0, 0, 0);
        }
    }
    int Tout = 2 * Tin;
    #pragma unroll
    for (int oj = 0; oj < OC / 32; oj++) {
        int oc = oj * 32 + lm;
        float bs = bias[oc];
        #pragma unroll
        for (int r = 0; r < 16; r++) {
            int m = m0 + ml + (r & 3) + 8 * (r >> 2) + 4 * lk;
            float ve = accE[oj][r] + bs;
            float vo = accO[oj][r] + bs;
            if (RELU) { ve = fmaxf(ve, 0.f); vo = fmaxf(vo, 0.f); }
            short* yp = y + ((size_t)b * Tout + 2 * m) * OC + oc;
            yp[0]  = f2bs(ve);
            yp[OC] = f2bs(vo);
        }
    }
}

// ---- convT3 (64->8) fp32 VALU from bf16 channels-last r2, fused recon MSE --
__global__ __launch_bounds__(256)
void convt3_loss(const short* __restrict__ r2, const float* __restrict__ w,
                 const float* __restrict__ bias, const float* __restrict__ x,
                 float* __restrict__ acc) {
    __shared__ float wl[64 * 8 * 4];
    __shared__ float bl[8];
    int tid = threadIdx.x;
    for (int idx = tid; idx < 2048; idx += 256) wl[idx] = w[idx];
    if (tid < 8) bl[tid] = bias[tid];
    __syncthreads();

    int m = blockIdx.x * 256 + tid;
    int b = blockIdx.z;
    const short* rb = r2 + (size_t)b * T1 * 64;
    float ae[8], ao[8];
    #pragma unroll
    for (int j = 0; j < 8; j++) { ae[j] = bl[j]; ao[j] = bl[j]; }
    short8 zz = {0, 0, 0, 0, 0, 0, 0, 0};
    for (int ic8 = 0; ic8 < 8; ic8++) {
        short8 sm = (m > 0)      ? *(const short8*)(rb + (size_t)(m - 1) * 64 + ic8 * 8) : zz;
        short8 s0 =                *(const short8*)(rb + (size_t)m * 64 + ic8 * 8);
        short8 sp = (m + 1 < T1) ? *(const short8*)(rb + (size_t)(m + 1) * 64 + ic8 * 8) : zz;
        #pragma unroll
        for (int l = 0; l < 8; l++) {
            float xm = b2f(sm[l]), x0 = b2f(s0[l]), xp = b2f(sp[l]);
            const float4* w4 = (const float4*)(wl + (ic8 * 8 + l) * 32);
            #pragma unroll
            for (int j = 0; j < 8; j++) {
                float4 wv = w4[j];
                ae[j] = fmaf(x0, wv.y, fmaf(xm, wv.w, ae[j]));
                ao[j] = fmaf(xp, wv.x, fmaf(x0, wv.z, ao[j]));
            }
        }
    }
    float s = 0.f;
    const float* xin = x + (size_t)b * 8 * T0;
    #pragma unroll
    for (int j = 0; j < 8; j++) {
        float de = ae[j] - xin[(size_t)j * T0 + 2 * m];
        float d1 = ao[j] - xin[(size_t)j * T0 + 2 * m + 1];
        s += de * de + d1 * d1;
    }
    s = block_sum256(s);
    if (tid == 0) atomicAdd(acc + 1, s);
}

// -------- prep: zero accumulators, codebook norms, weight transposes --------
__global__ void prep_kernel(const float* __restrict__ cb,
                            const float* __restrict__ w2, const float* __restrict__ w3,
                            const float* __restrict__ dw1, const float* __restrict__ dw2,
                            float* __restrict__ c2, float* __restrict__ cond,
                            float* __restrict__ acc,
                            short* __restrict__ wb2, short* __restrict__ wb3,
                            short* __restrict__ wT1, short* __restrict__ wT2) {
    int i = blockIdx.x * 256 + threadIdx.x;
    if (i < 8) acc[i] = 0.f;
    if (i < 1024) cond[i] = 0.f;
    if (i < NCODES) {
        float s = 0.f;
        #pragma unroll
        for (int d = 0; d < EDIM; d++) { float v = cb[i * EDIM + d]; s += v * v; }
        c2[i] = s;
    }
    // wb2[tap][oc][ic] <- w2[oc][ic][tap]  (5*128*64)
    if (i < 40960) {
        int tap = i / 8192, r = i - tap * 8192;        // r = oc*64+ic
        int oc = r >> 6, ic = r & 63;
        wb2[i] = f2bs(w2[((size_t)oc * 64 + ic) * 5 + tap]);
    }
    // wb3[tap][oc][ic] <- w3[oc][ic][tap]  (3*64*128)
    if (i < 24576) {
        int tap = i / 8192, r = i - tap * 8192;        // r = oc*128+ic
        int oc = r >> 7, ic = r & 127;
        wb3[i] = f2bs(w3[((size_t)oc * 128 + ic) * 3 + tap]);
    }
    // wT1[k][oc][ic] <- dw1[ic][oc][k]  (4*128*64)
    if (i < 32768) {
        int k = i / 8192, r = i - k * 8192;            // r = oc*64+ic
        int oc = r >> 6, ic = r & 63;
        wT1[i] = f2bs(dw1[((size_t)ic * 128 + oc) * 4 + k]);
    }
    // wT2[k][oc][ic] <- dw2[ic][oc][k]  (4*64*128)
    if (i < 32768) {
        int k = i / 8192, r = i - k * 8192;            // r = oc*128+ic
        int oc = r >> 7, ic = r & 127;
        wT2[i] = f2bs(dw2[((size_t)ic * 64 + oc) * 4 + k]);
    }
}

// -------- VQ: tiled GEMM + fused argmin + z_q(bf16) + cond accumulation -----
#define MT 128
#define NCH 128
__global__ __launch_bounds__(256, 2)
void quant_kernel(const float* __restrict__ ze,   // [b][T3][64] fp32
                  const float* __restrict__ cb, const float* __restrict__ c2g,
                  short* __restrict__ zq,          // [b][T3][64] bf16
                  float* __restrict__ cond, float* __restrict__ acc) {
    __shared__ float lA[64 * 132];   // [d][t]
    __shared__ float lB[64 * NCH];   // [d][c], reused as cond scratch
    __shared__ int   ibuf[MT];
    int tid = threadIdx.x;
    int bb = blockIdx.x >> 5;
    int t0 = (blockIdx.x & 31) * MT;
    {   // stage A transposed: ze rows [t][d] -> lA[d][t]
        int t  = tid >> 1;
        int dh = (tid & 1) * 32;
        const float4* src = (const float4*)(ze + ((size_t)(bb * T3 + t0 + t)) * 64 + dh);
        #pragma unroll
        for (int q = 0; q < 8; ++q) {
            float4 v = src[q];
            int d = dh + q * 4;
            lA[(d + 0) * 132 + t] = v.x;
            lA[(d + 1) * 132 + t] = v.y;
            lA[(d + 2) * 132 + t] = v.z;
            lA[(d + 3) * 132 + t] = v.w;
        }
    }
    int tx = tid & 15, ty = tid >> 4;
    float best[8];
    int   bidx[8];
    #pragma unroll
    for (int i = 0; i < 8; ++i) { best[i] = 3.4e38f; bidx[i] = 0; }

    for (int cc = 0; cc < NCODES / NCH; ++cc) {
        __syncthreads();
        {   // stage B chunk transposed: cb[c][d] -> lB[d][c]
            int c  = tid >> 1;
            int db = (tid & 1) * 32;
            const float4* src = (const float4*)(cb + ((size_t)(cc * NCH) + c) * EDIM + db);
            #pragma unroll
            for (int q = 0; q < 8; ++q) {
                float4 v = src[q];
                int d = db + q * 4;
                lB[(d + 0) * NCH + c] = v.x;
                lB[(d + 1) * NCH + c] = v.y;
                lB[(d + 2) * NCH + c] = v.z;
                lB[(d + 3) * NCH + c] = v.w;
            }
        }
        __syncthreads();
        float dot[8][8];
        #pragma unroll
        for (int i = 0; i < 8; ++i)
            #pragma unroll
            for (int j = 0; j < 8; ++j) dot[i][j] = 0.f;
        for (int d = 0; d < 64; ++d) {
            float4 a0 = *(const float4*)(lA + d * 132 + ty * 8);
            float4 a1 = *(const float4*)(lA + d * 132 + ty * 8 + 4);
            float4 b0 = *(const float4*)(lB + d * NCH + tx * 8);
            float4 b1 = *(const float4*)(lB + d * NCH + tx * 8 + 4);
            float av[8] = {a0.x, a0.y, a0.z, a0.w, a1.x, a1.y, a1.z, a1.w};
            float bv[8] = {b0.x, b0.y, b0.z, b0.w, b1.x, b1.y, b1.z, b1.w};
            #pragma unroll
            for (int i = 0; i < 8; ++i)
                #pragma unroll
                for (int j = 0; j < 8; ++j)
                    dot[i][j] = fmaf(av[i], bv[j], dot[i][j]);
        }
        float4 u0 = *(const float4*)(c2g + cc * NCH + tx * 8);
        float4 u1 = *(const float4*)(c2g + cc * NCH + tx * 8 + 4);
        float c2v[8] = {u0.x, u0.y, u0.z, u0.w, u1.x, u1.y, u1.z, u1.w};
        #pragma unroll
        for (int j = 0; j < 8; ++j) {
            int cidx = cc * NCH + tx * 8 + j;
            #pragma unroll
            for (int i = 0; i < 8; ++i) {
                float s = c2v[j] - 2.f * dot[i][j];
                if (s < best[i]) { best[i] = s; bidx[i] = cidx; }
            }
        }
    }
    #pragma unroll
    for (int i = 0; i < 8; ++i) {
        float bsc = best[i];
        int   bix = bidx[i];
        #pragma unroll
        for (int mm = 1; mm < 16; mm <<= 1) {
            float ob = __shfl_xor(bsc, mm, 64);
            int   oi = __shfl_xor(bix, mm, 64);
            if (ob < bsc || (ob == bsc && oi < bix)) { bsc = ob; bix = oi; }
        }
        if (tx == 0) ibuf[ty * 8 + i] = bix;
    }
    __syncthreads();
    // z_q write (bf16 channels-last) + vq-loss partial
    float vql = 0.f;
    {
        int t  = tid >> 1;
        int dh = (tid & 1) * 32;
        int code = ibuf[t];
        const float4* cv = (const float4*)(cb + (size_t)code * EDIM + dh);
        short* zqp = zq + ((size_t)(bb * T3 + t0 + t)) * 64 + dh;
        #pragma unroll
        for (int q = 0; q < 8; ++q) {
            float4 v = cv[q];
            float qq[4] = {v.x, v.y, v.z, v.w};
            short8 pk;
            #pragma unroll
            for (int l = 0; l < 4; ++l) {
                int d = dh + q * 4 + l;
                float zv = lA[(size_t)d * 132 + t];
                float df = zv - qq[l];
                vql += df * df;
            }
            // pack 4 bf16 (store as 2x short4 via scalar shorts)
            zqp[q * 4 + 0] = f2bs(qq[0]);
            zqp[q * 4 + 1] = f2bs(qq[1]);
            zqp[q * 4 + 2] = f2bs(qq[2]);
            zqp[q * 4 + 3] = f2bs(qq[3]);
        }
    }
    // conditioning: sum over tile of cb[code][d]
    {
        int d = tid & 63, g = tid >> 6;
        float s = 0.f;
        for (int t = g; t < MT; t += 4) s += cb[(size_t)ibuf[t] * EDIM + d];
        __syncthreads();                 // lB free now
        lB[g * 64 + d] = s;
        __syncthreads();
        if (tid < 64)
            atomicAdd(cond + bb * 64 + tid,
                      lB[tid] + lB[64 + tid] + lB[128 + tid] + lB[192 + tid]);
    }
    vql = block_sum256(vql);
    if (tid == 0) atomicAdd(acc, vql);
}

__global__ void fin_kernel(const float* __restrict__ cond,
                           const float* __restrict__ acc, float* __restrict__ out) {
    int i = threadIdx.x;   // 1024 threads
    out[i] = cond[i] * (1.f / (float)T3);
    if (i == 0) {
        float vq = acc[0] * (1.f / 4194304.f);   // B*D*T3
        out[1024] = vq;
        out[1025] = vq;
        out[1026] = acc[1] * (1.f / 4194304.f);  // B*C0*T0
    }
}

extern "C" void kernel_launch(void* const* d_in, const int* in_sizes, int n_in,
                              void* d_out, int out_size, void* d_ws, size_t ws_size,
                              hipStream_t stream) {
    const float* x   = (const float*)d_in[0];
    const float* w1  = (const float*)d_in[1];
    const float* b1  = (const float*)d_in[2];
    const float* w2  = (const float*)d_in[3];
    const float* b2  = (const float*)d_in[4];
    const float* w3  = (const float*)d_in[5];
    const float* b3  = (const float*)d_in[6];
    const float* cb  = (const float*)d_in[7];
    const float* dw1 = (const float*)d_in[8];
    const float* db1 = (const float*)d_in[9];
    const float* dw2 = (const float*)d_in[10];
    const float* db2 = (const float*)d_in[11];
    const float* dw3 = (const float*)d_in[12];
    const float* db3 = (const float*)d_in[13];
    float* out = (float*)d_out;

    char* ws = (char*)d_ws;
    short* a1  = (short*)(ws);                    // [16][16384][64] bf16; later r2
    short* a2  = (short*)(ws + 33554432);         // [16][8192][128] bf16; later r1
    float* ze  = (float*)(ws + 67108864);         // [16][4096][64] fp32
    short* zq  = (short*)(ws + 83886080);         // [16][4096][64] bf16
    short* wb2 = (short*)(ws + 92274688);
    short* wb3 = (short*)(ws + 92356608);
    short* wT1 = (short*)(ws + 92405760);
    short* wT2 = (short*)(ws + 92471296);
    float* c2  = (float*)(ws + 92536832);
    float* cnd = (float*)(ws + 92538880);
    float* acc = (float*)(ws + 92542976);

    prep_kernel<<<160, 256, 0, stream>>>(cb, w2, w3, dw1, dw2, c2, cnd, acc,
                                         wb2, wb3, wT1, wT2);
    conv1_kernel<<<dim3(32, 4, NB), 256, 0, stream>>>(x, w1, b1, a1);
    conv_mfma_fwd<64, 128, 5, 2, 128, 4, true, false>
        <<<dim3(T2 / 128, 1, NB), 256, 0, stream>>>(a1, wb2, b2, a2, T1, T2);
    conv_mfma_fwd<128, 64, 3, 1, 64, 2, false, true>
        <<<dim3(T3 / 64, 1, NB), 128, 0, stream>>>(a2, wb3, b3, ze, T2, T3);
    quant_kernel<<<NB * (T3 / MT), 256, 0, stream>>>(ze, cb, c2, zq, cnd, acc);
    conv_mfma_t<64, 128, 128, 4, true>
        <<<dim3(T3 / 128, 1, NB), 256, 0, stream>>>(zq, wT1, db1, a2, T3);
    conv_mfma_t<128, 64, 128, 4, true>
        <<<dim3(T2 / 128, 1, NB), 256, 0, stream>>>(a2, wT2, db2, a1, T2);
    convt3_loss<<<dim3(T1 / 256, 1, NB), 256, 0, stream>>>(a1, dw3, db3, x, acc);
    fin_kernel<<<1, 1024, 0, stream>>>(cnd, acc, out);
}

// Round 5
// 338.120 us; speedup vs baseline: 2.8734x; 1.0480x over previous
//
#include <hip/hip_runtime.h>
#include <hip/hip_bf16.h>

// VQ-VAE pipeline. Round 5: quant GEMM moved to bf16 MFMA (round-4: quant
// 75us top dispatch, fp32 VALU 8x8 tile w/ 4-way lB bank conflicts). z-tile
// bf16 in LDS (XOR swizzle), codebook bf16 [c][d] as B-frags from L2, fused
// argmin on MFMA scores with first-index tie-break; z_q/vq-loss epilogue
// reads z_e fp32 from global. Convs unchanged from round 4.

#define NB 16
#define T0 32768
#define T1 16384
#define T2 8192
#define T3 4096
#define NCODES 512
#define EDIM 64

typedef __attribute__((ext_vector_type(8)))  short short8;
typedef __attribute__((ext_vector_type(16))) float f32x16;

__device__ __forceinline__ float b2f(short s) {
    unsigned u = ((unsigned)(unsigned short)s) << 16;
    float f; __builtin_memcpy(&f, &u, 4); return f;
}
__device__ __forceinline__ short f2bs(float f) {
    __hip_bfloat16 h = __float2bfloat16(f);
    short s; __builtin_memcpy(&s, &h, 2); return s;
}

__device__ __forceinline__ float block_sum256(float v) {
    #pragma unroll
    for (int off = 32; off > 0; off >>= 1) v += __shfl_down(v, off, 64);
    __shared__ float red[4];
    int lane = threadIdx.x & 63, wv = threadIdx.x >> 6;
    if (lane == 0) red[wv] = v;
    __syncthreads();
    return red[0] + red[1] + red[2] + red[3];
}

// ---------------- conv1: fp32 VALU, 8ch in, 64ch out, k7 s2 p3 --------------
__global__ __launch_bounds__(256)
void conv1_kernel(const float* __restrict__ x, const float* __restrict__ w1,
                  const float* __restrict__ b1, short* __restrict__ y) {
    __shared__ float wt[8 * 7 * 16];
    __shared__ float bl[16];
    int tid = threadIdx.x;
    int ocg = blockIdx.y;
    for (int idx = tid; idx < 896; idx += 256) {
        int j = idx & 15, r = idx >> 4;
        int ic = r / 7, k = r - ic * 7;
        wt[idx] = w1[((size_t)(ocg * 16 + j) * 8 + ic) * 7 + k];
    }
    if (tid < 16) bl[tid] = b1[ocg * 16 + tid];
    __syncthreads();

    int t0 = blockIdx.x * 512 + tid;
    int b  = blockIdx.z;
    float acc[2][16];
    #pragma unroll
    for (int i = 0; i < 2; i++)
        #pragma unroll
        for (int j = 0; j < 16; j++) acc[i][j] = 0.f;
    for (int ic = 0; ic < 8; ic++) {
        const float* xr = x + ((size_t)b * 8 + ic) * T0;
        float xw[2][7];
        #pragma unroll
        for (int i = 0; i < 2; i++) {
            int p0 = 2 * (t0 + i * 256) - 3;
            #pragma unroll
            for (int k = 0; k < 7; k++) {
                int p = p0 + k;
                xw[i][k] = ((unsigned)p < (unsigned)T0) ? xr[p] : 0.f;
            }
        }
        #pragma unroll
        for (int k = 0; k < 7; k++) {
            const float4* w4 = (const float4*)(wt + (ic * 7 + k) * 16);
            #pragma unroll
            for (int j4 = 0; j4 < 4; j4++) {
                float4 wv = w4[j4];
                #pragma unroll
                for (int i = 0; i < 2; i++) {
                    acc[i][j4 * 4 + 0] = fmaf(xw[i][k], wv.x, acc[i][j4 * 4 + 0]);
                    acc[i][j4 * 4 + 1] = fmaf(xw[i][k], wv.y, acc[i][j4 * 4 + 1]);
                    acc[i][j4 * 4 + 2] = fmaf(xw[i][k], wv.z, acc[i][j4 * 4 + 2]);
                    acc[i][j4 * 4 + 3] = fmaf(xw[i][k], wv.w, acc[i][j4 * 4 + 3]);
                }
            }
        }
    }
    #pragma unroll
    for (int i = 0; i < 2; i++) {
        int t = t0 + i * 256;
        short8 s0, s1;
        #pragma unroll
        for (int j = 0; j < 8; j++) {
            float v0 = fmaxf(acc[i][j] + bl[j], 0.f);
            float v1 = fmaxf(acc[i][j + 8] + bl[j + 8], 0.f);
            s0[j] = f2bs(v0); s1[j] = f2bs(v1);
        }
        short* yp = y + ((size_t)b * T1 + t) * 64 + ocg * 16;
        *(short8*)(yp)     = s0;
        *(short8*)(yp + 8) = s1;
    }
}

// --------- MFMA forward conv: stride 2, channels-last bf16 ------------------
template<int IC, int OC, int TAPS, int PAD, int BT, int NW, bool RELU, bool F32OUT>
__global__ __launch_bounds__(NW * 64, 2)
void conv_mfma_fwd(const short* __restrict__ x, const short* __restrict__ wb,
                   const float* __restrict__ bias, void* __restrict__ yout,
                   int Tin, int Tout) {
    constexpr int C8 = IC / 8;
    constexpr int NR = 2 * (BT - 1) + TAPS;
    __shared__ short lx[NR * IC];
    const int tid = threadIdx.x;
    const int b   = blockIdx.z;
    const int t0  = blockIdx.x * BT;
    const int r0  = 2 * t0 - PAD;
    const short* xg = x + (size_t)b * Tin * IC;
    short8 zz = {0, 0, 0, 0, 0, 0, 0, 0};
    for (int idx = tid; idx < NR * C8; idx += NW * 64) {
        int row = idx / C8, c8 = idx - row * C8;
        int gr = r0 + row;
        short8 v = zz;
        if ((unsigned)gr < (unsigned)Tin)
            v = *(const short8*)(xg + (size_t)gr * IC + c8 * 8);
        int sw = c8 ^ ((row >> 1) & (C8 - 1));
        *(short8*)(lx + row * IC + sw * 8) = v;
    }
    __syncthreads();

    const int wv = tid >> 6, lane = tid & 63;
    const int tl = wv * 32;
    const int lm = lane & 31, lk = lane >> 5;
    f32x16 acc[OC / 32];
    #pragma unroll
    for (int oj = 0; oj < OC / 32; oj++)
        #pragma unroll
        for (int r = 0; r < 16; r++) acc[oj][r] = 0.f;

    #pragma unroll
    for (int tap = 0; tap < TAPS; tap++) {
        #pragma unroll
        for (int kc = 0; kc < IC / 16; kc++) {
            int row = 2 * (tl + lm) + tap;
            int c8  = kc * 2 + lk;
            int sw  = c8 ^ ((row >> 1) & (C8 - 1));
            short8 a = *(const short8*)(lx + row * IC + sw * 8);
            const short* wg = wb + ((size_t)tap * OC + lm) * IC + kc * 16 + lk * 8;
            #pragma unroll
            for (int oj = 0; oj < OC / 32; oj++) {
                short8 bf = *(const short8*)(wg + (size_t)oj * 32 * IC);
                acc[oj] = __builtin_amdgcn_mfma_f32_32x32x16_bf16(a, bf, acc[oj], 0, 0, 0);
            }
        }
    }
    #pragma unroll
    for (int oj = 0; oj < OC / 32; oj++) {
        int oc = oj * 32 + lm;
        float bs = bias[oc];
        #pragma unroll
        for (int r = 0; r < 16; r++) {
            int t = t0 + tl + (r & 3) + 8 * (r >> 2) + 4 * lk;
            float v = acc[oj][r] + bs;
            if (RELU) v = fmaxf(v, 0.f);
            if (F32OUT)
                ((float*)yout)[((size_t)b * Tout + t) * OC + oc] = v;
            else
                ((short*)yout)[((size_t)b * Tout + t) * OC + oc] = f2bs(v);
        }
    }
}

// --------- MFMA conv-transpose (k4 s2 p1), both parities --------------------
template<int IC, int OC, int BT, int NW, bool RELU>
__global__ __launch_bounds__(NW * 64, 2)
void conv_mfma_t(const short* __restrict__ x, const short* __restrict__ wb,
                 const float* __restrict__ bias, short* __restrict__ y, int Tin) {
    constexpr int C8 = IC / 8;
    constexpr int NR = BT + 2;
    __shared__ short lx[NR * IC];
    const int tid = threadIdx.x;
    const int b   = blockIdx.z;
    const int m0  = blockIdx.x * BT;
    const int r0  = m0 - 1;
    const short* xg = x + (size_t)b * Tin * IC;
    short8 zz = {0, 0, 0, 0, 0, 0, 0, 0};
    for (int idx = tid; idx < NR * C8; idx += NW * 64) {
        int row = idx / C8, c8 = idx - row * C8;
        int gr = r0 + row;
        short8 v = zz;
        if ((unsigned)gr < (unsigned)Tin)
            v = *(const short8*)(xg + (size_t)gr * IC + c8 * 8);
        int sw = c8 ^ ((row >> 1) & (C8 - 1));
        *(short8*)(lx + row * IC + sw * 8) = v;
    }
    __syncthreads();

    const int wv = tid >> 6, lane = tid & 63;
    const int ml = wv * 32;
    const int lm = lane & 31, lk = lane >> 5;
    f32x16 accE[OC / 32], accO[OC / 32];
    #pragma unroll
    for (int oj = 0; oj < OC / 32; oj++)
        #pragma unroll
        for (int r = 0; r < 16; r++) { accE[oj][r] = 0.f; accO[oj][r] = 0.f; }

    #pragma unroll
    for (int kc = 0; kc < IC / 16; kc++) {
        int c8 = kc * 2 + lk;
        int rA = (ml + lm);
        short8 a_m1, a_0, a_p1;
        {
            int row = rA;
            a_m1 = *(const short8*)(lx + row * IC + (c8 ^ ((row >> 1) & (C8 - 1))) * 8);
            row = rA + 1;
            a_0  = *(const short8*)(lx + row * IC + (c8 ^ ((row >> 1) & (C8 - 1))) * 8);
            row = rA + 2;
            a_p1 = *(const short8*)(lx + row * IC + (c8 ^ ((row >> 1) & (C8 - 1))) * 8);
        }
        const short* wg = wb + (size_t)lm * IC + kc * 16 + lk * 8;
        #pragma unroll
        for (int oj = 0; oj < OC / 32; oj++) {
            const short* wo = wg + (size_t)oj * 32 * IC;
            short8 w0 = *(const short8*)(wo);
            short8 w1 = *(const short8*)(wo + (size_t)1 * OC * IC);
            short8 w2 = *(const short8*)(wo + (size_t)2 * OC * IC);
            short8 w3 = *(const short8*)(wo + (size_t)3 * OC * IC);
            accE[oj] = __builtin_amdgcn_mfma_f32_32x32x16_bf16(a_0,  w1, accE[oj], 0, 0, 0);
            accE[oj] = __builtin_amdgcn_mfma_f32_32x32x16_bf16(a_m1, w3, accE[oj], 0, 0, 0);
            accO[oj] = __builtin_amdgcn_mfma_f32_32x32x16_bf16(a_p1, w0, accO[oj], 0, 0, 0);
            accO[oj] = __builtin_amdgcn_mfma_f32_32x32x16_bf16(a_0,  w2, accO[oj], 0, 0, 0);
        }
    }
    int Tout = 2 * Tin;
    #pragma unroll
    for (int oj = 0; oj < OC / 32; oj++) {
        int oc = oj * 32 + lm;
        float bs = bias[oc];
        #pragma unroll
        for (int r = 0; r < 16; r++) {
            int m = m0 + ml + (r & 3) + 8 * (r >> 2) + 4 * lk;
            float ve = accE[oj][r] + bs;
            float vo = accO[oj][r] + bs;
            if (RELU) { ve = fmaxf(ve, 0.f); vo = fmaxf(vo, 0.f); }
            short* yp = y + ((size_t)b * Tout + 2 * m) * OC + oc;
            yp[0]  = f2bs(ve);
            yp[OC] = f2bs(vo);
        }
    }
}

// ---- convT3 (64->8) fp32 VALU from bf16 channels-last r2, fused recon MSE --
__global__ __launch_bounds__(256)
void convt3_loss(const short* __restrict__ r2, const float* __restrict__ w,
                 const float* __restrict__ bias, const float* __restrict__ x,
                 float* __restrict__ acc) {
    __shared__ float wl[64 * 8 * 4];
    __shared__ float bl[8];
    int tid = threadIdx.x;
    for (int idx = tid; idx < 2048; idx += 256) wl[idx] = w[idx];
    if (tid < 8) bl[tid] = bias[tid];
    __syncthreads();

    int m = blockIdx.x * 256 + tid;
    int b = blockIdx.z;
    const short* rb = r2 + (size_t)b * T1 * 64;
    float ae[8], ao[8];
    #pragma unroll
    for (int j = 0; j < 8; j++) { ae[j] = bl[j]; ao[j] = bl[j]; }
    short8 zz = {0, 0, 0, 0, 0, 0, 0, 0};
    for (int ic8 = 0; ic8 < 8; ic8++) {
        short8 sm = (m > 0)      ? *(const short8*)(rb + (size_t)(m - 1) * 64 + ic8 * 8) : zz;
        short8 s0 =                *(const short8*)(rb + (size_t)m * 64 + ic8 * 8);
        short8 sp = (m + 1 < T1) ? *(const short8*)(rb + (size_t)(m + 1) * 64 + ic8 * 8) : zz;
        #pragma unroll
        for (int l = 0; l < 8; l++) {
            float xm = b2f(sm[l]), x0 = b2f(s0[l]), xp = b2f(sp[l]);
            const float4* w4 = (const float4*)(wl + (ic8 * 8 + l) * 32);
            #pragma unroll
            for (int j = 0; j < 8; j++) {
                float4 wv = w4[j];
                ae[j] = fmaf(x0, wv.y, fmaf(xm, wv.w, ae[j]));
                ao[j] = fmaf(xp, wv.x, fmaf(x0, wv.z, ao[j]));
            }
        }
    }
    float s = 0.f;
    const float* xin = x + (size_t)b * 8 * T0;
    #pragma unroll
    for (int j = 0; j < 8; j++) {
        float de = ae[j] - xin[(size_t)j * T0 + 2 * m];
        float d1 = ao[j] - xin[(size_t)j * T0 + 2 * m + 1];
        s += de * de + d1 * d1;
    }
    s = block_sum256(s);
    if (tid == 0) atomicAdd(acc + 1, s);
}

// -------- prep: zero accumulators, codebook norms+bf16, weight transposes ---
__global__ void prep_kernel(const float* __restrict__ cb,
                            const float* __restrict__ w2, const float* __restrict__ w3,
                            const float* __restrict__ dw1, const float* __restrict__ dw2,
                            float* __restrict__ c2, float* __restrict__ cond,
                            float* __restrict__ acc,
                            short* __restrict__ wb2, short* __restrict__ wb3,
                            short* __restrict__ wT1, short* __restrict__ wT2,
                            short* __restrict__ cbbf) {
    int i = blockIdx.x * 256 + threadIdx.x;
    if (i < 8) acc[i] = 0.f;
    if (i < 1024) cond[i] = 0.f;
    if (i < NCODES) {
        float s = 0.f;
        #pragma unroll
        for (int d = 0; d < EDIM; d++) { float v = cb[i * EDIM + d]; s += v * v; }
        c2[i] = s;
    }
    if (i < 32768) cbbf[i] = f2bs(cb[i]);      // [c][d] bf16
    if (i < 40960) {
        int tap = i / 8192, r = i - tap * 8192;
        int oc = r >> 6, ic = r & 63;
        wb2[i] = f2bs(w2[((size_t)oc * 64 + ic) * 5 + tap]);
    }
    if (i < 24576) {
        int tap = i / 8192, r = i - tap * 8192;
        int oc = r >> 7, ic = r & 127;
        wb3[i] = f2bs(w3[((size_t)oc * 128 + ic) * 3 + tap]);
    }
    if (i < 32768) {
        int k = i / 8192, r = i - k * 8192;
        int oc = r >> 6, ic = r & 63;
        wT1[i] = f2bs(dw1[((size_t)ic * 128 + oc) * 4 + k]);
    }
    if (i < 32768) {
        int k = i / 8192, r = i - k * 8192;
        int oc = r >> 7, ic = r & 127;
        wT2[i] = f2bs(dw2[((size_t)ic * 64 + oc) * 4 + k]);
    }
}

// -------- VQ via MFMA: 128t tile, scores=|c|^2-2*dot, fused argmin ----------
__global__ __launch_bounds__(256, 2)
void quant_kernel(const float* __restrict__ ze,   // [b][T3][64] fp32
                  const float* __restrict__ cb, const short* __restrict__ cbbf,
                  const float* __restrict__ c2g,
                  short* __restrict__ zq,          // [b][T3][64] bf16
                  float* __restrict__ cond, float* __restrict__ acc) {
    __shared__ short lx[128 * 64];    // bf16 A-tile, rows XOR-swizzled
    __shared__ int   ibuf[128];
    __shared__ float cscr[256];
    __shared__ float lc2[NCODES];
    int tid = threadIdx.x;
    int bb = blockIdx.x >> 5;
    int t0 = (blockIdx.x & 31) * 128;
    const float* zrow = ze + ((size_t)(bb * T3 + t0)) * 64;
    for (int i = tid; i < NCODES; i += 256) lc2[i] = c2g[i];
    // stage A: 128 rows x 64 ch fp32 -> bf16, swizzle c8 ^= (row & 7)
    for (int task = tid; task < 1024; task += 256) {
        int row = task >> 3, c8 = task & 7;
        const float4* s = (const float4*)(zrow + row * 64 + c8 * 8);
        float4 v0 = s[0], v1 = s[1];
        short8 p;
        p[0] = f2bs(v0.x); p[1] = f2bs(v0.y); p[2] = f2bs(v0.z); p[3] = f2bs(v0.w);
        p[4] = f2bs(v1.x); p[5] = f2bs(v1.y); p[6] = f2bs(v1.z); p[7] = f2bs(v1.w);
        *(short8*)(lx + row * 64 + (c8 ^ (row & 7)) * 8) = p;
    }
    __syncthreads();
    int wv = tid >> 6, lane = tid & 63, lm = lane & 31, lk = lane >> 5;
    // A-frags (4 K-slices of 16), reused across all 16 code-tiles
    short8 afr[4];
    int arow = wv * 32 + lm;
    #pragma unroll
    for (int kc = 0; kc < 4; kc++) {
        int c8 = kc * 2 + lk;
        afr[kc] = *(const short8*)(lx + arow * 64 + (c8 ^ (arow & 7)) * 8);
    }
    float best[16];
    int   bidx[16];
    #pragma unroll
    for (int r = 0; r < 16; r++) { best[r] = 3.4e38f; bidx[r] = 0; }
    for (int ct = 0; ct < 16; ct++) {
        f32x16 a;
        #pragma unroll
        for (int r = 0; r < 16; r++) a[r] = 0.f;
        const short* wg = cbbf + ((size_t)(ct * 32 + lm)) * 64 + lk * 8;
        #pragma unroll
        for (int kc = 0; kc < 4; kc++) {
            short8 bf = *(const short8*)(wg + kc * 16);
            a = __builtin_amdgcn_mfma_f32_32x32x16_bf16(afr[kc], bf, a, 0, 0, 0);
        }
        int   cidx = ct * 32 + lm;      // per-lane candidates ascend with ct
        float c2v  = lc2[cidx];
        #pragma unroll
        for (int r = 0; r < 16; r++) {
            float s = c2v - 2.f * a[r];
            if (s < best[r]) { best[r] = s; bidx[r] = cidx; }
        }
    }
    // cross-lane argmin over the 32 lm-lanes (lk preserved by masks<32)
    #pragma unroll
    for (int r = 0; r < 16; r++) {
        float s = best[r];
        int   i = bidx[r];
        #pragma unroll
        for (int mk = 1; mk < 32; mk <<= 1) {
            float os = __shfl_xor(s, mk, 64);
            int   oi = __shfl_xor(i, mk, 64);
            if (os < s || (os == s && oi < i)) { s = os; i = oi; }
        }
        if (lm == 0) ibuf[wv * 32 + (r & 3) + 8 * (r >> 2) + 4 * lk] = i;
    }
    __syncthreads();
    // epilogue: z_q (bf16 channels-last, vector stores) + vq-loss partial
    float vql = 0.f;
    {
        int t = tid >> 1, dh = (tid & 1) * 32;
        int code = ibuf[t];
        const float4* cv = (const float4*)(cb + (size_t)code * 64 + dh);
        const float4* zv = (const float4*)(zrow + (size_t)t * 64 + dh);
        short* zqp = zq + ((size_t)(bb * T3 + t0 + t)) * 64 + dh;
        #pragma unroll
        for (int q = 0; q < 4; q++) {
            float4 c0 = cv[2 * q], c1 = cv[2 * q + 1];
            float4 z0 = zv[2 * q], z1 = zv[2 * q + 1];
            float d;
            d = z0.x - c0.x; vql += d * d;
            d = z0.y - c0.y; vql += d * d;
            d = z0.z - c0.z; vql += d * d;
            d = z0.w - c0.w; vql += d * d;
            d = z1.x - c1.x; vql += d * d;
            d = z1.y - c1.y; vql += d * d;
            d = z1.z - c1.z; vql += d * d;
            d = z1.w - c1.w; vql += d * d;
            short8 p;
            p[0] = f2bs(c0.x); p[1] = f2bs(c0.y); p[2] = f2bs(c0.z); p[3] = f2bs(c0.w);
            p[4] = f2bs(c1.x); p[5] = f2bs(c1.y); p[6] = f2bs(c1.z); p[7] = f2bs(c1.w);
            *(short8*)(zqp + q * 8) = p;
        }
    }
    // conditioning: per-batch sum over tile of cb[code][d]
    {
        int d = tid & 63, g = tid >> 6;
        float s = 0.f;
        for (int t = g; t < 128; t += 4) s += cb[(size_t)ibuf[t] * 64 + d];
        cscr[g * 64 + d] = s;
        __syncthreads();
        if (tid < 64)
            atomicAdd(cond + bb * 64 + tid,
                      cscr[tid] + cscr[64 + tid] + cscr[128 + tid] + cscr[192 + tid]);
    }
    vql = block_sum256(vql);
    if (tid == 0) atomicAdd(acc, vql);
}

__global__ void fin_kernel(const float* __restrict__ cond,
                           const float* __restrict__ acc, float* __restrict__ out) {
    int i = threadIdx.x;   // 1024 threads
    out[i] = cond[i] * (1.f / (float)T3);
    if (i == 0) {
        float vq = acc[0] * (1.f / 4194304.f);   // B*D*T3
        out[1024] = vq;
        out[1025] = vq;
        out[1026] = acc[1] * (1.f / 4194304.f);  // B*C0*T0
    }
}

extern "C" void kernel_launch(void* const* d_in, const int* in_sizes, int n_in,
                              void* d_out, int out_size, void* d_ws, size_t ws_size,
                              hipStream_t stream) {
    const float* x   = (const float*)d_in[0];
    const float* w1  = (const float*)d_in[1];
    const float* b1  = (const float*)d_in[2];
    const float* w2  = (const float*)d_in[3];
    const float* b2  = (const float*)d_in[4];
    const float* w3  = (const float*)d_in[5];
    const float* b3  = (const float*)d_in[6];
    const float* cb  = (const float*)d_in[7];
    const float* dw1 = (const float*)d_in[8];
    const float* db1 = (const float*)d_in[9];
    const float* dw2 = (const float*)d_in[10];
    const float* db2 = (const float*)d_in[11];
    const float* dw3 = (const float*)d_in[12];
    const float* db3 = (const float*)d_in[13];
    float* out = (float*)d_out;

    char* ws = (char*)d_ws;
    short* a1   = (short*)(ws);                    // [16][16384][64] bf16; later r2
    short* a2   = (short*)(ws + 33554432);         // [16][8192][128] bf16; later r1
    float* ze   = (float*)(ws + 67108864);         // [16][4096][64] fp32
    short* zq   = (short*)(ws + 83886080);         // [16][4096][64] bf16
    short* wb2  = (short*)(ws + 92274688);
    short* wb3  = (short*)(ws + 92356608);
    short* wT1  = (short*)(ws + 92405760);
    short* wT2  = (short*)(ws + 92471296);
    short* cbbf = (short*)(ws + 92536832);         // [512][64] bf16
    float* c2   = (float*)(ws + 92602368);
    float* cnd  = (float*)(ws + 92604416);
    float* acc  = (float*)(ws + 92608512);

    prep_kernel<<<160, 256, 0, stream>>>(cb, w2, w3, dw1, dw2, c2, cnd, acc,
                                         wb2, wb3, wT1, wT2, cbbf);
    conv1_kernel<<<dim3(32, 4, NB), 256, 0, stream>>>(x, w1, b1, a1);
    conv_mfma_fwd<64, 128, 5, 2, 128, 4, true, false>
        <<<dim3(T2 / 128, 1, NB), 256, 0, stream>>>(a1, wb2, b2, a2, T1, T2);
    conv_mfma_fwd<128, 64, 3, 1, 64, 2, false, true>
        <<<dim3(T3 / 64, 1, NB), 128, 0, stream>>>(a2, wb3, b3, ze, T2, T3);
    quant_kernel<<<NB * (T3 / 128), 256, 0, stream>>>(ze, cb, cbbf, c2, zq, cnd, acc);
    conv_mfma_t<64, 128, 128, 4, true>
        <<<dim3(T3 / 128, 1, NB), 256, 0, stream>>>(zq, wT1, db1, a2, T3);
    conv_mfma_t<128, 64, 128, 4, true>
        <<<dim3(T2 / 128, 1, NB), 256, 0, stream>>>(a2, wT2, db2, a1, T2);
    convt3_loss<<<dim3(T1 / 256, 1, NB), 256, 0, stream>>>(a1, dw3, db3, x, acc);
    fin_kernel<<<1, 1024, 0, stream>>>(cnd, acc, out);
}

// Round 6
// 329.559 us; speedup vs baseline: 2.9481x; 1.0260x over previous
//
#include <hip/hip_runtime.h>
#include <hip/hip_bf16.h>

// VQ-VAE pipeline. Round 6: quant argmin de-spilled (round-5: VGPR_Count=44
// proves best[16]/bidx[16] spilled to scratch -> 60us latency-bound, both
// pipes <11%). New: per-ct MFMA scores go to an LDS scoreboard scr[t][c]
// (stride 33, double-buffered, 1 barrier/ct); each thread scans its own
// (t, 16-code half) with SCALAR best/bidx. Convs unchanged from round 5.

#define NB 16
#define T0 32768
#define T1 16384
#define T2 8192
#define T3 4096
#define NCODES 512
#define EDIM 64

typedef __attribute__((ext_vector_type(8)))  short short8;
typedef __attribute__((ext_vector_type(16))) float f32x16;

__device__ __forceinline__ float b2f(short s) {
    unsigned u = ((unsigned)(unsigned short)s) << 16;
    float f; __builtin_memcpy(&f, &u, 4); return f;
}
__device__ __forceinline__ short f2bs(float f) {
    __hip_bfloat16 h = __float2bfloat16(f);
    short s; __builtin_memcpy(&s, &h, 2); return s;
}

__device__ __forceinline__ float block_sum256(float v) {
    #pragma unroll
    for (int off = 32; off > 0; off >>= 1) v += __shfl_down(v, off, 64);
    __shared__ float red[4];
    int lane = threadIdx.x & 63, wv = threadIdx.x >> 6;
    if (lane == 0) red[wv] = v;
    __syncthreads();
    return red[0] + red[1] + red[2] + red[3];
}

// ---------------- conv1: fp32 VALU, 8ch in, 64ch out, k7 s2 p3 --------------
__global__ __launch_bounds__(256)
void conv1_kernel(const float* __restrict__ x, const float* __restrict__ w1,
                  const float* __restrict__ b1, short* __restrict__ y) {
    __shared__ float wt[8 * 7 * 16];
    __shared__ float bl[16];
    int tid = threadIdx.x;
    int ocg = blockIdx.y;
    for (int idx = tid; idx < 896; idx += 256) {
        int j = idx & 15, r = idx >> 4;
        int ic = r / 7, k = r - ic * 7;
        wt[idx] = w1[((size_t)(ocg * 16 + j) * 8 + ic) * 7 + k];
    }
    if (tid < 16) bl[tid] = b1[ocg * 16 + tid];
    __syncthreads();

    int t0 = blockIdx.x * 512 + tid;
    int b  = blockIdx.z;
    float acc[2][16];
    #pragma unroll
    for (int i = 0; i < 2; i++)
        #pragma unroll
        for (int j = 0; j < 16; j++) acc[i][j] = 0.f;
    for (int ic = 0; ic < 8; ic++) {
        const float* xr = x + ((size_t)b * 8 + ic) * T0;
        float xw[2][7];
        #pragma unroll
        for (int i = 0; i < 2; i++) {
            int p0 = 2 * (t0 + i * 256) - 3;
            #pragma unroll
            for (int k = 0; k < 7; k++) {
                int p = p0 + k;
                xw[i][k] = ((unsigned)p < (unsigned)T0) ? xr[p] : 0.f;
            }
        }
        #pragma unroll
        for (int k = 0; k < 7; k++) {
            const float4* w4 = (const float4*)(wt + (ic * 7 + k) * 16);
            #pragma unroll
            for (int j4 = 0; j4 < 4; j4++) {
                float4 wv = w4[j4];
                #pragma unroll
                for (int i = 0; i < 2; i++) {
                    acc[i][j4 * 4 + 0] = fmaf(xw[i][k], wv.x, acc[i][j4 * 4 + 0]);
                    acc[i][j4 * 4 + 1] = fmaf(xw[i][k], wv.y, acc[i][j4 * 4 + 1]);
                    acc[i][j4 * 4 + 2] = fmaf(xw[i][k], wv.z, acc[i][j4 * 4 + 2]);
                    acc[i][j4 * 4 + 3] = fmaf(xw[i][k], wv.w, acc[i][j4 * 4 + 3]);
                }
            }
        }
    }
    #pragma unroll
    for (int i = 0; i < 2; i++) {
        int t = t0 + i * 256;
        short8 s0, s1;
        #pragma unroll
        for (int j = 0; j < 8; j++) {
            float v0 = fmaxf(acc[i][j] + bl[j], 0.f);
            float v1 = fmaxf(acc[i][j + 8] + bl[j + 8], 0.f);
            s0[j] = f2bs(v0); s1[j] = f2bs(v1);
        }
        short* yp = y + ((size_t)b * T1 + t) * 64 + ocg * 16;
        *(short8*)(yp)     = s0;
        *(short8*)(yp + 8) = s1;
    }
}

// --------- MFMA forward conv: stride 2, channels-last bf16 ------------------
template<int IC, int OC, int TAPS, int PAD, int BT, int NW, bool RELU, bool F32OUT>
__global__ __launch_bounds__(NW * 64, 2)
void conv_mfma_fwd(const short* __restrict__ x, const short* __restrict__ wb,
                   const float* __restrict__ bias, void* __restrict__ yout,
                   int Tin, int Tout) {
    constexpr int C8 = IC / 8;
    constexpr int NR = 2 * (BT - 1) + TAPS;
    __shared__ short lx[NR * IC];
    const int tid = threadIdx.x;
    const int b   = blockIdx.z;
    const int t0  = blockIdx.x * BT;
    const int r0  = 2 * t0 - PAD;
    const short* xg = x + (size_t)b * Tin * IC;
    short8 zz = {0, 0, 0, 0, 0, 0, 0, 0};
    for (int idx = tid; idx < NR * C8; idx += NW * 64) {
        int row = idx / C8, c8 = idx - row * C8;
        int gr = r0 + row;
        short8 v = zz;
        if ((unsigned)gr < (unsigned)Tin)
            v = *(const short8*)(xg + (size_t)gr * IC + c8 * 8);
        int sw = c8 ^ ((row >> 1) & (C8 - 1));
        *(short8*)(lx + row * IC + sw * 8) = v;
    }
    __syncthreads();

    const int wv = tid >> 6, lane = tid & 63;
    const int tl = wv * 32;
    const int lm = lane & 31, lk = lane >> 5;
    f32x16 acc[OC / 32];
    #pragma unroll
    for (int oj = 0; oj < OC / 32; oj++)
        #pragma unroll
        for (int r = 0; r < 16; r++) acc[oj][r] = 0.f;

    #pragma unroll
    for (int tap = 0; tap < TAPS; tap++) {
        #pragma unroll
        for (int kc = 0; kc < IC / 16; kc++) {
            int row = 2 * (tl + lm) + tap;
            int c8  = kc * 2 + lk;
            int sw  = c8 ^ ((row >> 1) & (C8 - 1));
            short8 a = *(const short8*)(lx + row * IC + sw * 8);
            const short* wg = wb + ((size_t)tap * OC + lm) * IC + kc * 16 + lk * 8;
            #pragma unroll
            for (int oj = 0; oj < OC / 32; oj++) {
                short8 bf = *(const short8*)(wg + (size_t)oj * 32 * IC);
                acc[oj] = __builtin_amdgcn_mfma_f32_32x32x16_bf16(a, bf, acc[oj], 0, 0, 0);
            }
        }
    }
    #pragma unroll
    for (int oj = 0; oj < OC / 32; oj++) {
        int oc = oj * 32 + lm;
        float bs = bias[oc];
        #pragma unroll
        for (int r = 0; r < 16; r++) {
            int t = t0 + tl + (r & 3) + 8 * (r >> 2) + 4 * lk;
            float v = acc[oj][r] + bs;
            if (RELU) v = fmaxf(v, 0.f);
            if (F32OUT)
                ((float*)yout)[((size_t)b * Tout + t) * OC + oc] = v;
            else
                ((short*)yout)[((size_t)b * Tout + t) * OC + oc] = f2bs(v);
        }
    }
}

// --------- MFMA conv-transpose (k4 s2 p1), both parities --------------------
template<int IC, int OC, int BT, int NW, bool RELU>
__global__ __launch_bounds__(NW * 64, 2)
void conv_mfma_t(const short* __restrict__ x, const short* __restrict__ wb,
                 const float* __restrict__ bias, short* __restrict__ y, int Tin) {
    constexpr int C8 = IC / 8;
    constexpr int NR = BT + 2;
    __shared__ short lx[NR * IC];
    const int tid = threadIdx.x;
    const int b   = blockIdx.z;
    const int m0  = blockIdx.x * BT;
    const int r0  = m0 - 1;
    const short* xg = x + (size_t)b * Tin * IC;
    short8 zz = {0, 0, 0, 0, 0, 0, 0, 0};
    for (int idx = tid; idx < NR * C8; idx += NW * 64) {
        int row = idx / C8, c8 = idx - row * C8;
        int gr = r0 + row;
        short8 v = zz;
        if ((unsigned)gr < (unsigned)Tin)
            v = *(const short8*)(xg + (size_t)gr * IC + c8 * 8);
        int sw = c8 ^ ((row >> 1) & (C8 - 1));
        *(short8*)(lx + row * IC + sw * 8) = v;
    }
    __syncthreads();

    const int wv = tid >> 6, lane = tid & 63;
    const int ml = wv * 32;
    const int lm = lane & 31, lk = lane >> 5;
    f32x16 accE[OC / 32], accO[OC / 32];
    #pragma unroll
    for (int oj = 0; oj < OC / 32; oj++)
        #pragma unroll
        for (int r = 0; r < 16; r++) { accE[oj][r] = 0.f; accO[oj][r] = 0.f; }

    #pragma unroll
    for (int kc = 0; kc < IC / 16; kc++) {
        int c8 = kc * 2 + lk;
        int rA = (ml + lm);
        short8 a_m1, a_0, a_p1;
        {
            int row = rA;
            a_m1 = *(const short8*)(lx + row * IC + (c8 ^ ((row >> 1) & (C8 - 1))) * 8);
            row = rA + 1;
            a_0  = *(const short8*)(lx + row * IC + (c8 ^ ((row >> 1) & (C8 - 1))) * 8);
            row = rA + 2;
            a_p1 = *(const short8*)(lx + row * IC + (c8 ^ ((row >> 1) & (C8 - 1))) * 8);
        }
        const short* wg = wb + (size_t)lm * IC + kc * 16 + lk * 8;
        #pragma unroll
        for (int oj = 0; oj < OC / 32; oj++) {
            const short* wo = wg + (size_t)oj * 32 * IC;
            short8 w0 = *(const short8*)(wo);
            short8 w1 = *(const short8*)(wo + (size_t)1 * OC * IC);
            short8 w2 = *(const short8*)(wo + (size_t)2 * OC * IC);
            short8 w3 = *(const short8*)(wo + (size_t)3 * OC * IC);
            accE[oj] = __builtin_amdgcn_mfma_f32_32x32x16_bf16(a_0,  w1, accE[oj], 0, 0, 0);
            accE[oj] = __builtin_amdgcn_mfma_f32_32x32x16_bf16(a_m1, w3, accE[oj], 0, 0, 0);
            accO[oj] = __builtin_amdgcn_mfma_f32_32x32x16_bf16(a_p1, w0, accO[oj], 0, 0, 0);
            accO[oj] = __builtin_amdgcn_mfma_f32_32x32x16_bf16(a_0,  w2, accO[oj], 0, 0, 0);
        }
    }
    int Tout = 2 * Tin;
    #pragma unroll
    for (int oj = 0; oj < OC / 32; oj++) {
        int oc = oj * 32 + lm;
        float bs = bias[oc];
        #pragma unroll
        for (int r = 0; r < 16; r++) {
            int m = m0 + ml + (r & 3) + 8 * (r >> 2) + 4 * lk;
            float ve = accE[oj][r] + bs;
            float vo = accO[oj][r] + bs;
            if (RELU) { ve = fmaxf(ve, 0.f); vo = fmaxf(vo, 0.f); }
            short* yp = y + ((size_t)b * Tout + 2 * m) * OC + oc;
            yp[0]  = f2bs(ve);
            yp[OC] = f2bs(vo);
        }
    }
}

// ---- convT3 (64->8) fp32 VALU from bf16 channels-last r2, fused recon MSE --
__global__ __launch_bounds__(256)
void convt3_loss(const short* __restrict__ r2, const float* __restrict__ w,
                 const float* __restrict__ bias, const float* __restrict__ x,
                 float* __restrict__ acc) {
    __shared__ float wl[64 * 8 * 4];
    __shared__ float bl[8];
    int tid = threadIdx.x;
    for (int idx = tid; idx < 2048; idx += 256) wl[idx] = w[idx];
    if (tid < 8) bl[tid] = bias[tid];
    __syncthreads();

    int m = blockIdx.x * 256 + tid;
    int b = blockIdx.z;
    const short* rb = r2 + (size_t)b * T1 * 64;
    float ae[8], ao[8];
    #pragma unroll
    for (int j = 0; j < 8; j++) { ae[j] = bl[j]; ao[j] = bl[j]; }
    short8 zz = {0, 0, 0, 0, 0, 0, 0, 0};
    for (int ic8 = 0; ic8 < 8; ic8++) {
        short8 sm = (m > 0)      ? *(const short8*)(rb + (size_t)(m - 1) * 64 + ic8 * 8) : zz;
        short8 s0 =                *(const short8*)(rb + (size_t)m * 64 + ic8 * 8);
        short8 sp = (m + 1 < T1) ? *(const short8*)(rb + (size_t)(m + 1) * 64 + ic8 * 8) : zz;
        #pragma unroll
        for (int l = 0; l < 8; l++) {
            float xm = b2f(sm[l]), x0 = b2f(s0[l]), xp = b2f(sp[l]);
            const float4* w4 = (const float4*)(wl + (ic8 * 8 + l) * 32);
            #pragma unroll
            for (int j = 0; j < 8; j++) {
                float4 wv = w4[j];
                ae[j] = fmaf(x0, wv.y, fmaf(xm, wv.w, ae[j]));
                ao[j] = fmaf(xp, wv.x, fmaf(x0, wv.z, ao[j]));
            }
        }
    }
    float s = 0.f;
    const float* xin = x + (size_t)b * 8 * T0;
    #pragma unroll
    for (int j = 0; j < 8; j++) {
        float de = ae[j] - xin[(size_t)j * T0 + 2 * m];
        float d1 = ao[j] - xin[(size_t)j * T0 + 2 * m + 1];
        s += de * de + d1 * d1;
    }
    s = block_sum256(s);
    if (tid == 0) atomicAdd(acc + 1, s);
}

// -------- prep: zero accumulators, codebook norms+bf16, weight transposes ---
__global__ void prep_kernel(const float* __restrict__ cb,
                            const float* __restrict__ w2, const float* __restrict__ w3,
                            const float* __restrict__ dw1, const float* __restrict__ dw2,
                            float* __restrict__ c2, float* __restrict__ cond,
                            float* __restrict__ acc,
                            short* __restrict__ wb2, short* __restrict__ wb3,
                            short* __restrict__ wT1, short* __restrict__ wT2,
                            short* __restrict__ cbbf) {
    int i = blockIdx.x * 256 + threadIdx.x;
    if (i < 8) acc[i] = 0.f;
    if (i < 1024) cond[i] = 0.f;
    if (i < NCODES) {
        float s = 0.f;
        #pragma unroll
        for (int d = 0; d < EDIM; d++) { float v = cb[i * EDIM + d]; s += v * v; }
        c2[i] = s;
    }
    if (i < 32768) cbbf[i] = f2bs(cb[i]);      // [c][d] bf16
    if (i < 40960) {
        int tap = i / 8192, r = i - tap * 8192;
        int oc = r >> 6, ic = r & 63;
        wb2[i] = f2bs(w2[((size_t)oc * 64 + ic) * 5 + tap]);
    }
    if (i < 24576) {
        int tap = i / 8192, r = i - tap * 8192;
        int oc = r >> 7, ic = r & 127;
        wb3[i] = f2bs(w3[((size_t)oc * 128 + ic) * 3 + tap]);
    }
    if (i < 32768) {
        int k = i / 8192, r = i - k * 8192;
        int oc = r >> 6, ic = r & 63;
        wT1[i] = f2bs(dw1[((size_t)ic * 128 + oc) * 4 + k]);
    }
    if (i < 32768) {
        int k = i / 8192, r = i - k * 8192;
        int oc = r >> 7, ic = r & 127;
        wT2[i] = f2bs(dw2[((size_t)ic * 64 + oc) * 4 + k]);
    }
}

// -------- VQ via MFMA + LDS scoreboard argmin (scalar best/bidx) ------------
__global__ __launch_bounds__(256, 2)
void quant_kernel(const float* __restrict__ ze,   // [b][T3][64] fp32
                  const float* __restrict__ cb, const short* __restrict__ cbbf,
                  const float* __restrict__ c2g,
                  short* __restrict__ zq,          // [b][T3][64] bf16
                  float* __restrict__ cond, float* __restrict__ acc) {
    __shared__ short lx[128 * 64];      // bf16 A-tile, rows XOR-swizzled
    __shared__ float scr[2][128 * 33];  // score buffers [t][c], stride 33
    __shared__ int   ibuf[128];
    __shared__ float cscr[1024];
    __shared__ float lc2[NCODES];
    int tid = threadIdx.x;
    int bb = blockIdx.x >> 5;
    int t0 = (blockIdx.x & 31) * 128;
    const float* zrow = ze + ((size_t)(bb * T3 + t0)) * 64;
    for (int i = tid; i < NCODES; i += 256) lc2[i] = c2g[i];
    // stage A: 128 rows x 64 ch fp32 -> bf16, swizzle c8 ^= (row & 7)
    for (int task = tid; task < 1024; task += 256) {
        int row = task >> 3, c8 = task & 7;
        const float4* s = (const float4*)(zrow + row * 64 + c8 * 8);
        float4 v0 = s[0], v1 = s[1];
        short8 p;
        p[0] = f2bs(v0.x); p[1] = f2bs(v0.y); p[2] = f2bs(v0.z); p[3] = f2bs(v0.w);
        p[4] = f2bs(v1.x); p[5] = f2bs(v1.y); p[6] = f2bs(v1.z); p[7] = f2bs(v1.w);
        *(short8*)(lx + row * 64 + (c8 ^ (row & 7)) * 8) = p;
    }
    __syncthreads();
    int wv = tid >> 6, lane = tid & 63, lm = lane & 31, lk = lane >> 5;
    short8 afr[4];
    int arow = wv * 32 + lm;
    #pragma unroll
    for (int kc = 0; kc < 4; kc++) {
        int c8 = kc * 2 + lk;
        afr[kc] = *(const short8*)(lx + arow * 64 + (c8 ^ (arow & 7)) * 8);
    }
    // per-thread argmin state: SCALARS (round-5's arrays spilled to scratch)
    int   tq   = tid >> 1;
    int   c0   = (tid & 1) * 16;
    float best = 3.4e38f;
    int   bidx = 0;
    for (int ct = 0; ct < 16; ct++) {
        f32x16 a;
        #pragma unroll
        for (int r = 0; r < 16; r++) a[r] = 0.f;
        const short* wg = cbbf + ((size_t)(ct * 32 + lm)) * 64 + lk * 8;
        #pragma unroll
        for (int kc = 0; kc < 4; kc++) {
            short8 bf = *(const short8*)(wg + kc * 16);
            a = __builtin_amdgcn_mfma_f32_32x32x16_bf16(afr[kc], bf, a, 0, 0, 0);
        }
        float c2v = lc2[ct * 32 + lm];
        float* sb = scr[ct & 1];
        #pragma unroll
        for (int r = 0; r < 16; r++) {
            int tl = wv * 32 + (r & 3) + 8 * (r >> 2) + 4 * lk;
            sb[tl * 33 + lm] = c2v - 2.f * a[r];   // 32 consecutive words/row
        }
        __syncthreads();     // double-buffer: one barrier per ct is enough
        const float* sr = sb + tq * 33 + c0;
        #pragma unroll
        for (int j = 0; j < 16; j++) {             // ascending code order
            float s = sr[j];
            if (s < best) { best = s; bidx = ct * 32 + c0 + j; }
        }
    }
    // merge the two 16-code halves per t (adjacent lanes), first-index ties
    {
        float os = __shfl_xor(best, 1, 64);
        int   oi = __shfl_xor(bidx, 1, 64);
        if (os < best || (os == best && oi < bidx)) { best = os; bidx = oi; }
        if ((tid & 1) == 0) ibuf[tq] = bidx;
    }
    __syncthreads();
    // epilogue: z_q (bf16 channels-last, vector stores) + vq-loss partial
    float vql = 0.f;
    {
        int t = tid >> 1, dh = (tid & 1) * 32;
        int code = ibuf[t];
        const float4* cv = (const float4*)(cb + (size_t)code * 64 + dh);
        const float4* zv = (const float4*)(zrow + (size_t)t * 64 + dh);
        short* zqp = zq + ((size_t)(bb * T3 + t0 + t)) * 64 + dh;
        #pragma unroll
        for (int q = 0; q < 4; q++) {
            float4 c0v = cv[2 * q], c1v = cv[2 * q + 1];
            float4 z0 = zv[2 * q], z1 = zv[2 * q + 1];
            float d;
            d = z0.x - c0v.x; vql += d * d;
            d = z0.y - c0v.y; vql += d * d;
            d = z0.z - c0v.z; vql += d * d;
            d = z0.w - c0v.w; vql += d * d;
            d = z1.x - c1v.x; vql += d * d;
            d = z1.y - c1v.y; vql += d * d;
            d = z1.z - c1v.z; vql += d * d;
            d = z1.w - c1v.w; vql += d * d;
            short8 p;
            p[0] = f2bs(c0v.x); p[1] = f2bs(c0v.y); p[2] = f2bs(c0v.z); p[3] = f2bs(c0v.w);
            p[4] = f2bs(c1v.x); p[5] = f2bs(c1v.y); p[6] = f2bs(c1v.z); p[7] = f2bs(c1v.w);
            *(short8*)(zqp + q * 8) = p;
        }
    }
    // conditioning: per-batch sum over tile of cb[code][d], float4 gather
    {
        int d4 = (tid & 15) * 4;
        int g  = tid >> 4;
        float4 s4 = {0.f, 0.f, 0.f, 0.f};
        for (int t = g; t < 128; t += 16) {
            float4 v = *(const float4*)(cb + (size_t)ibuf[t] * 64 + d4);
            s4.x += v.x; s4.y += v.y; s4.z += v.z; s4.w += v.w;
        }
        *(float4*)(cscr + g * 64 + d4) = s4;
        __syncthreads();
        if (tid < 64) {
            float s = 0.f;
            #pragma unroll
            for (int g2 = 0; g2 < 16; g2++) s += cscr[g2 * 64 + tid];
            atomicAdd(cond + bb * 64 + tid, s);
        }
    }
    vql = block_sum256(vql);
    if (tid == 0) atomicAdd(acc, vql);
}

__global__ void fin_kernel(const float* __restrict__ cond,
                           const float* __restrict__ acc, float* __restrict__ out) {
    int i = threadIdx.x;   // 1024 threads
    out[i] = cond[i] * (1.f / (float)T3);
    if (i == 0) {
        float vq = acc[0] * (1.f / 4194304.f);   // B*D*T3
        out[1024] = vq;
        out[1025] = vq;
        out[1026] = acc[1] * (1.f / 4194304.f);  // B*C0*T0
    }
}

extern "C" void kernel_launch(void* const* d_in, const int* in_sizes, int n_in,
                              void* d_out, int out_size, void* d_ws, size_t ws_size,
                              hipStream_t stream) {
    const float* x   = (const float*)d_in[0];
    const float* w1  = (const float*)d_in[1];
    const float* b1  = (const float*)d_in[2];
    const float* w2  = (const float*)d_in[3];
    const float* b2  = (const float*)d_in[4];
    const float* w3  = (const float*)d_in[5];
    const float* b3  = (const float*)d_in[6];
    const float* cb  = (const float*)d_in[7];
    const float* dw1 = (const float*)d_in[8];
    const float* db1 = (const float*)d_in[9];
    const float* dw2 = (const float*)d_in[10];
    const float* db2 = (const float*)d_in[11];
    const float* dw3 = (const float*)d_in[12];
    const float* db3 = (const float*)d_in[13];
    float* out = (float*)d_out;

    char* ws = (char*)d_ws;
    short* a1   = (short*)(ws);                    // [16][16384][64] bf16; later r2
    short* a2   = (short*)(ws + 33554432);         // [16][8192][128] bf16; later r1
    float* ze   = (float*)(ws + 67108864);         // [16][4096][64] fp32
    short* zq   = (short*)(ws + 83886080);         // [16][4096][64] bf16
    short* wb2  = (short*)(ws + 92274688);
    short* wb3  = (short*)(ws + 92356608);
    short* wT1  = (short*)(ws + 92405760);
    short* wT2  = (short*)(ws + 92471296);
    short* cbbf = (short*)(ws + 92536832);         // [512][64] bf16
    float* c2   = (float*)(ws + 92602368);
    float* cnd  = (float*)(ws + 92604416);
    float* acc  = (float*)(ws + 92608512);

    prep_kernel<<<160, 256, 0, stream>>>(cb, w2, w3, dw1, dw2, c2, cnd, acc,
                                         wb2, wb3, wT1, wT2, cbbf);
    conv1_kernel<<<dim3(32, 4, NB), 256, 0, stream>>>(x, w1, b1, a1);
    conv_mfma_fwd<64, 128, 5, 2, 128, 4, true, false>
        <<<dim3(T2 / 128, 1, NB), 256, 0, stream>>>(a1, wb2, b2, a2, T1, T2);
    conv_mfma_fwd<128, 64, 3, 1, 64, 2, false, true>
        <<<dim3(T3 / 64, 1, NB), 128, 0, stream>>>(a2, wb3, b3, ze, T2, T3);
    quant_kernel<<<NB * (T3 / 128), 256, 0, stream>>>(ze, cb, cbbf, c2, zq, cnd, acc);
    conv_mfma_t<64, 128, 128, 4, true>
        <<<dim3(T3 / 128, 1, NB), 256, 0, stream>>>(zq, wT1, db1, a2, T3);
    conv_mfma_t<128, 64, 128, 4, true>
        <<<dim3(T2 / 128, 1, NB), 256, 0, stream>>>(a2, wT2, db2, a1, T2);
    convt3_loss<<<dim3(T1 / 256, 1, NB), 256, 0, stream>>>(a1, dw3, db3, x, acc);
    fin_kernel<<<1, 1024, 0, stream>>>(cnd, acc, out);
}

// Round 7
// 296.480 us; speedup vs baseline: 3.2770x; 1.1116x over previous
//
#include <hip/hip_runtime.h>
#include <hip/hip_bf16.h>

// VQ-VAE pipeline. Round 7: kill per-wave L2 weight re-loads (round-6: conv2
// 50us with MfmaUtil 7.7%/VALUBusy 7.5% -> latency-bound; each wave streamed
// the full 80KB weight array from L2 = 327MB aggregate). Weights now staged
// once/block in LDS (XOR swizzle), oc-split grids keep 2-3 blocks/CU.
// conv1 rewritten as MFMA im2col (K=8ic*7tap pad 64). convt3 LDS-staged.

#define NB 16
#define T0 32768
#define T1 16384
#define T2 8192
#define T3 4096
#define NCODES 512
#define EDIM 64

typedef __attribute__((ext_vector_type(8)))  short short8;
typedef __attribute__((ext_vector_type(16))) float f32x16;

__device__ __forceinline__ float b2f(short s) {
    unsigned u = ((unsigned)(unsigned short)s) << 16;
    float f; __builtin_memcpy(&f, &u, 4); return f;
}
__device__ __forceinline__ short f2bs(float f) {
    __hip_bfloat16 h = __float2bfloat16(f);
    short s; __builtin_memcpy(&s, &h, 2); return s;
}

__device__ __forceinline__ float block_sum256(float v) {
    #pragma unroll
    for (int off = 32; off > 0; off >>= 1) v += __shfl_down(v, off, 64);
    __shared__ float red[4];
    int lane = threadIdx.x & 63, wv = threadIdx.x >> 6;
    if (lane == 0) red[wv] = v;
    __syncthreads();
    return red[0] + red[1] + red[2] + red[3];
}

// ---------------- conv1 via MFMA im2col: K = tap*8+ic (56, padded 64) -------
// x [b][8][T0] fp32 -> y [b][T1][64] bf16. w1b [64oc][64k] bf16 (prep).
__global__ __launch_bounds__(256, 2)
void conv1_mfma(const float* __restrict__ x, const short* __restrict__ w1b,
                const float* __restrict__ b1, short* __restrict__ y) {
    constexpr int BT = 128, NR = 262;
    __shared__ short lxc[NR * 8];     // [row][ic], row = 2*t0-3+r
    __shared__ short lw[64 * 64];     // [oc][k], slot c8 ^= (oc&7)
    int tid = threadIdx.x, b = blockIdx.z, t0 = blockIdx.x * BT;
    for (int i = tid; i < 512; i += 256) {
        int oc = i >> 3, c8 = i & 7;
        short8 v = *(const short8*)(w1b + oc * 64 + c8 * 8);
        *(short8*)(lw + oc * 64 + (c8 ^ (oc & 7)) * 8) = v;
    }
    for (int r = tid; r < NR; r += 256) {
        int g = 2 * t0 - 3 + r;
        short8 p;
        bool ok = (unsigned)g < (unsigned)T0;
        #pragma unroll
        for (int ic = 0; ic < 8; ic++) {
            float v = ok ? x[((size_t)b * 8 + ic) * T0 + g] : 0.f;
            p[ic] = f2bs(v);
        }
        *(short8*)(lxc + r * 8) = p;
    }
    __syncthreads();
    int wv = tid >> 6, lane = tid & 63, lm = lane & 31, lk = lane >> 5;
    int ml = wv * 32 + lm;
    f32x16 acc[2];
    #pragma unroll
    for (int oj = 0; oj < 2; oj++)
        #pragma unroll
        for (int r = 0; r < 16; r++) acc[oj][r] = 0.f;
    #pragma unroll
    for (int kc = 0; kc < 4; kc++) {
        int q = kc * 2 + lk;                       // tap (q=7: B rows are zero)
        short8 a = *(const short8*)(lxc + (2 * ml + q) * 8);
        #pragma unroll
        for (int oj = 0; oj < 2; oj++) {
            int oc = oj * 32 + lm;
            short8 bf = *(const short8*)(lw + oc * 64 + (q ^ (oc & 7)) * 8);
            acc[oj] = __builtin_amdgcn_mfma_f32_32x32x16_bf16(a, bf, acc[oj], 0, 0, 0);
        }
    }
    #pragma unroll
    for (int oj = 0; oj < 2; oj++) {
        int oc = oj * 32 + lm;
        float bs = b1[oc];
        #pragma unroll
        for (int r = 0; r < 16; r++) {
            int t = t0 + wv * 32 + (r & 3) + 8 * (r >> 2) + 4 * lk;
            float v = fmaxf(acc[oj][r] + bs, 0.f);
            y[((size_t)b * T1 + t) * 64 + oc] = f2bs(v);
        }
    }
}

// --------- MFMA forward conv, weights in LDS, oc-split ----------------------
template<int IC, int OC, int OCB, int TAPS, int PAD, int BT, int NW, bool RELU, bool F32OUT>
__global__ __launch_bounds__(NW * 64, 2)
void conv_mfma_fwd(const short* __restrict__ x, const short* __restrict__ wb,
                   const float* __restrict__ bias, void* __restrict__ yout,
                   int Tin, int Tout) {
    constexpr int C8 = IC / 8;
    constexpr int NR = 2 * (BT - 1) + TAPS;
    __shared__ short lw[TAPS * OCB * IC];
    __shared__ short lx[NR * IC];
    const int tid = threadIdx.x;
    const int b   = blockIdx.z;
    const int ocg = blockIdx.y * OCB;
    const int t0  = blockIdx.x * BT;
    const int r0  = 2 * t0 - PAD;
    // stage weights once per block: wb [tap][OC][IC] -> lw [tap][ocl][ic]
    for (int i = tid; i < TAPS * OCB * C8; i += NW * 64) {
        int tap = i / (OCB * C8), rem = i - tap * OCB * C8;
        int ocl = rem / C8, c8 = rem - ocl * C8;
        short8 v = *(const short8*)(wb + ((size_t)tap * OC + ocg + ocl) * IC + c8 * 8);
        *(short8*)(lw + (tap * OCB + ocl) * IC + (c8 ^ (ocl & (C8 - 1))) * 8) = v;
    }
    const short* xg = x + (size_t)b * Tin * IC;
    short8 zz = {0, 0, 0, 0, 0, 0, 0, 0};
    for (int idx = tid; idx < NR * C8; idx += NW * 64) {
        int row = idx / C8, c8 = idx - row * C8;
        int gr = r0 + row;
        short8 v = zz;
        if ((unsigned)gr < (unsigned)Tin)
            v = *(const short8*)(xg + (size_t)gr * IC + c8 * 8);
        *(short8*)(lx + row * IC + (c8 ^ ((row >> 1) & (C8 - 1))) * 8) = v;
    }
    __syncthreads();

    const int wv = tid >> 6, lane = tid & 63;
    const int tl = wv * 32;
    const int lm = lane & 31, lk = lane >> 5;
    f32x16 acc[OCB / 32];
    #pragma unroll
    for (int oj = 0; oj < OCB / 32; oj++)
        #pragma unroll
        for (int r = 0; r < 16; r++) acc[oj][r] = 0.f;

    #pragma unroll
    for (int tap = 0; tap < TAPS; tap++) {
        #pragma unroll
        for (int kc = 0; kc < IC / 16; kc++) {
            int row = 2 * (tl + lm) + tap;
            int c8  = kc * 2 + lk;
            short8 a = *(const short8*)(lx + row * IC + (c8 ^ ((row >> 1) & (C8 - 1))) * 8);
            #pragma unroll
            for (int oj = 0; oj < OCB / 32; oj++) {
                int ocl = oj * 32 + lm;
                short8 bf = *(const short8*)(lw + (tap * OCB + ocl) * IC +
                                             (c8 ^ (ocl & (C8 - 1))) * 8);
                acc[oj] = __builtin_amdgcn_mfma_f32_32x32x16_bf16(a, bf, acc[oj], 0, 0, 0);
            }
        }
    }
    #pragma unroll
    for (int oj = 0; oj < OCB / 32; oj++) {
        int oc = ocg + oj * 32 + lm;
        float bs = bias[oc];
        #pragma unroll
        for (int r = 0; r < 16; r++) {
            int t = t0 + tl + (r & 3) + 8 * (r >> 2) + 4 * lk;
            float v = acc[oj][r] + bs;
            if (RELU) v = fmaxf(v, 0.f);
            if (F32OUT)
                ((float*)yout)[((size_t)b * Tout + t) * OC + oc] = v;
            else
                ((short*)yout)[((size_t)b * Tout + t) * OC + oc] = f2bs(v);
        }
    }
}

// --------- MFMA conv-transpose (k4 s2 p1), weights in LDS, oc-split ---------
template<int IC, int OC, int OCB, int BT, int NW, bool RELU>
__global__ __launch_bounds__(NW * 64, 2)
void conv_mfma_t(const short* __restrict__ x, const short* __restrict__ wb,
                 const float* __restrict__ bias, short* __restrict__ y, int Tin) {
    constexpr int C8 = IC / 8;
    constexpr int NR = BT + 2;
    __shared__ short lw[4 * OCB * IC];
    __shared__ short lx[NR * IC];
    const int tid = threadIdx.x;
    const int b   = blockIdx.z;
    const int ocg = blockIdx.y * OCB;
    const int m0  = blockIdx.x * BT;
    const int r0  = m0 - 1;
    for (int i = tid; i < 4 * OCB * C8; i += NW * 64) {
        int k = i / (OCB * C8), rem = i - k * OCB * C8;
        int ocl = rem / C8, c8 = rem - ocl * C8;
        short8 v = *(const short8*)(wb + ((size_t)k * OC + ocg + ocl) * IC + c8 * 8);
        *(short8*)(lw + (k * OCB + ocl) * IC + (c8 ^ (ocl & (C8 - 1))) * 8) = v;
    }
    const short* xg = x + (size_t)b * Tin * IC;
    short8 zz = {0, 0, 0, 0, 0, 0, 0, 0};
    for (int idx = tid; idx < NR * C8; idx += NW * 64) {
        int row = idx / C8, c8 = idx - row * C8;
        int gr = r0 + row;
        short8 v = zz;
        if ((unsigned)gr < (unsigned)Tin)
            v = *(const short8*)(xg + (size_t)gr * IC + c8 * 8);
        *(short8*)(lx + row * IC + (c8 ^ ((row >> 1) & (C8 - 1))) * 8) = v;
    }
    __syncthreads();

    const int wv = tid >> 6, lane = tid & 63;
    const int ml = wv * 32;
    const int lm = lane & 31, lk = lane >> 5;
    f32x16 accE[OCB / 32], accO[OCB / 32];
    #pragma unroll
    for (int oj = 0; oj < OCB / 32; oj++)
        #pragma unroll
        for (int r = 0; r < 16; r++) { accE[oj][r] = 0.f; accO[oj][r] = 0.f; }

    #pragma unroll
    for (int kc = 0; kc < IC / 16; kc++) {
        int c8 = kc * 2 + lk;
        int rA = ml + lm;
        short8 a_m1, a_0, a_p1;
        {
            int row = rA;
            a_m1 = *(const short8*)(lx + row * IC + (c8 ^ ((row >> 1) & (C8 - 1))) * 8);
            row = rA + 1;
            a_0  = *(const short8*)(lx + row * IC + (c8 ^ ((row >> 1) & (C8 - 1))) * 8);
            row = rA + 2;
            a_p1 = *(const short8*)(lx + row * IC + (c8 ^ ((row >> 1) & (C8 - 1))) * 8);
        }
        #pragma unroll
        for (int oj = 0; oj < OCB / 32; oj++) {
            int ocl = oj * 32 + lm;
            int sw = (c8 ^ (ocl & (C8 - 1))) * 8;
            short8 w0 = *(const short8*)(lw + ((0 * OCB + ocl) * IC) + sw);
            short8 w1 = *(const short8*)(lw + ((1 * OCB + ocl) * IC) + sw);
            short8 w2 = *(const short8*)(lw + ((2 * OCB + ocl) * IC) + sw);
            short8 w3 = *(const short8*)(lw + ((3 * OCB + ocl) * IC) + sw);
            accE[oj] = __builtin_amdgcn_mfma_f32_32x32x16_bf16(a_0,  w1, accE[oj], 0, 0, 0);
            accE[oj] = __builtin_amdgcn_mfma_f32_32x32x16_bf16(a_m1, w3, accE[oj], 0, 0, 0);
            accO[oj] = __builtin_amdgcn_mfma_f32_32x32x16_bf16(a_p1, w0, accO[oj], 0, 0, 0);
            accO[oj] = __builtin_amdgcn_mfma_f32_32x32x16_bf16(a_0,  w2, accO[oj], 0, 0, 0);
        }
    }
    int Tout = 2 * Tin;
    #pragma unroll
    for (int oj = 0; oj < OCB / 32; oj++) {
        int oc = ocg + oj * 32 + lm;
        float bs = bias[oc];
        #pragma unroll
        for (int r = 0; r < 16; r++) {
            int m = m0 + ml + (r & 3) + 8 * (r >> 2) + 4 * lk;
            float ve = accE[oj][r] + bs;
            float vo = accO[oj][r] + bs;
            if (RELU) { ve = fmaxf(ve, 0.f); vo = fmaxf(vo, 0.f); }
            short* yp = y + ((size_t)b * Tout + 2 * m) * OC + oc;
            yp[0]  = f2bs(ve);
            yp[OC] = f2bs(vo);
        }
    }
}

// ---- convT3 (64->8) fused recon MSE, all inputs staged in LDS --------------
__global__ __launch_bounds__(256, 2)
void convt3_loss(const short* __restrict__ r2, const float* __restrict__ w,
                 const float* __restrict__ bias, const float* __restrict__ x,
                 float* __restrict__ acc) {
    __shared__ short lr[258 * 64];    // rows m0-1..m0+256, slot c8 ^= (r&7)
    __shared__ float lxt[8 * 512];    // x[j][2*m0 .. 2*m0+511]
    __shared__ float wl[2048];
    __shared__ float bl[8];
    int tid = threadIdx.x, b = blockIdx.z;
    int m0 = blockIdx.x * 256;
    for (int i = tid; i < 2048; i += 256) wl[i] = w[i];
    if (tid < 8) bl[tid] = bias[tid];
    const short* rb = r2 + (size_t)b * T1 * 64;
    short8 zz = {0, 0, 0, 0, 0, 0, 0, 0};
    for (int i = tid; i < 258 * 8; i += 256) {
        int r = i >> 3, c8 = i & 7;
        int g = m0 - 1 + r;
        short8 v = zz;
        if ((unsigned)g < (unsigned)T1)
            v = *(const short8*)(rb + (size_t)g * 64 + c8 * 8);
        *(short8*)(lr + r * 64 + (c8 ^ (r & 7)) * 8) = v;
    }
    const float* xb = x + (size_t)b * 8 * T0;
    for (int i = tid; i < 1024; i += 256) {
        int j = i >> 7, c4 = (i & 127) * 4;
        *(float4*)(lxt + j * 512 + c4) = *(const float4*)(xb + (size_t)j * T0 + 2 * m0 + c4);
    }
    __syncthreads();

    int ml = tid;                      // local m; r-center = ml+1
    float ae[8], ao[8];
    #pragma unroll
    for (int j = 0; j < 8; j++) { ae[j] = bl[j]; ao[j] = bl[j]; }
    for (int ic8 = 0; ic8 < 8; ic8++) {
        int r;
        r = ml;     short8 sm = *(const short8*)(lr + r * 64 + ((ic8 ^ (r & 7))) * 8);
        r = ml + 1; short8 s0 = *(const short8*)(lr + r * 64 + ((ic8 ^ (r & 7))) * 8);
        r = ml + 2; short8 sp = *(const short8*)(lr + r * 64 + ((ic8 ^ (r & 7))) * 8);
        #pragma unroll
        for (int l = 0; l < 8; l++) {
            float xm = b2f(sm[l]), x0 = b2f(s0[l]), xp = b2f(sp[l]);
            const float4* w4 = (const float4*)(wl + (ic8 * 8 + l) * 32);
            #pragma unroll
            for (int j = 0; j < 8; j++) {
                float4 wv = w4[j];
                ae[j] = fmaf(x0, wv.y, fmaf(xm, wv.w, ae[j]));
                ao[j] = fmaf(xp, wv.x, fmaf(x0, wv.z, ao[j]));
            }
        }
    }
    float s = 0.f;
    #pragma unroll
    for (int j = 0; j < 8; j++) {
        float de = ae[j] - lxt[j * 512 + 2 * ml];
        float d1 = ao[j] - lxt[j * 512 + 2 * ml + 1];
        s += de * de + d1 * d1;
    }
    s = block_sum256(s);
    if (tid == 0) atomicAdd(acc + 1, s);
}

// -------- prep: accumulators, codebook norms+bf16, weight transposes --------
__global__ void prep_kernel(const float* __restrict__ cb, const float* __restrict__ w1,
                            const float* __restrict__ w2, const float* __restrict__ w3,
                            const float* __restrict__ dw1, const float* __restrict__ dw2,
                            float* __restrict__ c2, float* __restrict__ cond,
                            float* __restrict__ acc,
                            short* __restrict__ wb2, short* __restrict__ wb3,
                            short* __restrict__ wT1, short* __restrict__ wT2,
                            short* __restrict__ cbbf, short* __restrict__ w1b) {
    int i = blockIdx.x * 256 + threadIdx.x;
    if (i < 8) acc[i] = 0.f;
    if (i < 1024) cond[i] = 0.f;
    if (i < NCODES) {
        float s = 0.f;
        #pragma unroll
        for (int d = 0; d < EDIM; d++) { float v = cb[i * EDIM + d]; s += v * v; }
        c2[i] = s;
    }
    if (i < 32768) cbbf[i] = f2bs(cb[i]);      // [c][d] bf16
    if (i < 4096) {                            // w1b[oc][k], k=tap*8+ic, pad 0
        int oc = i >> 6, k = i & 63;
        int ic = k & 7, q = k >> 3;
        w1b[i] = (q < 7) ? f2bs(w1[((size_t)oc * 8 + ic) * 7 + q]) : (short)0;
    }
    if (i < 40960) {
        int tap = i / 8192, r = i - tap * 8192;
        int oc = r >> 6, ic = r & 63;
        wb2[i] = f2bs(w2[((size_t)oc * 64 + ic) * 5 + tap]);
    }
    if (i < 24576) {
        int tap = i / 8192, r = i - tap * 8192;
        int oc = r >> 7, ic = r & 127;
        wb3[i] = f2bs(w3[((size_t)oc * 128 + ic) * 3 + tap]);
    }
    if (i < 32768) {
        int k = i / 8192, r = i - k * 8192;
        int oc = r >> 6, ic = r & 63;
        wT1[i] = f2bs(dw1[((size_t)ic * 128 + oc) * 4 + k]);
    }
    if (i < 32768) {
        int k = i / 8192, r = i - k * 8192;
        int oc = r >> 7, ic = r & 127;
        wT2[i] = f2bs(dw2[((size_t)ic * 64 + oc) * 4 + k]);
    }
}

// -------- VQ via MFMA + LDS scoreboard argmin (round-6, unchanged) ----------
__global__ __launch_bounds__(256, 2)
void quant_kernel(const float* __restrict__ ze, const float* __restrict__ cb,
                  const short* __restrict__ cbbf, const float* __restrict__ c2g,
                  short* __restrict__ zq, float* __restrict__ cond,
                  float* __restrict__ acc) {
    __shared__ short lx[128 * 64];
    __shared__ float scr[2][128 * 33];
    __shared__ int   ibuf[128];
    __shared__ float cscr[1024];
    __shared__ float lc2[NCODES];
    int tid = threadIdx.x;
    int bb = blockIdx.x >> 5;
    int t0 = (blockIdx.x & 31) * 128;
    const float* zrow = ze + ((size_t)(bb * T3 + t0)) * 64;
    for (int i = tid; i < NCODES; i += 256) lc2[i] = c2g[i];
    for (int task = tid; task < 1024; task += 256) {
        int row = task >> 3, c8 = task & 7;
        const float4* s = (const float4*)(zrow + row * 64 + c8 * 8);
        float4 v0 = s[0], v1 = s[1];
        short8 p;
        p[0] = f2bs(v0.x); p[1] = f2bs(v0.y); p[2] = f2bs(v0.z); p[3] = f2bs(v0.w);
        p[4] = f2bs(v1.x); p[5] = f2bs(v1.y); p[6] = f2bs(v1.z); p[7] = f2bs(v1.w);
        *(short8*)(lx + row * 64 + (c8 ^ (row & 7)) * 8) = p;
    }
    __syncthreads();
    int wv = tid >> 6, lane = tid & 63, lm = lane & 31, lk = lane >> 5;
    short8 afr[4];
    int arow = wv * 32 + lm;
    #pragma unroll
    for (int kc = 0; kc < 4; kc++) {
        int c8 = kc * 2 + lk;
        afr[kc] = *(const short8*)(lx + arow * 64 + (c8 ^ (arow & 7)) * 8);
    }
    int   tq = tid >> 1;
    int   c0 = (tid & 1) * 16;
    float best = 3.4e38f;
    int   bidx = 0;
    for (int ct = 0; ct < 16; ct++) {
        f32x16 a;
        #pragma unroll
        for (int r = 0; r < 16; r++) a[r] = 0.f;
        const short* wg = cbbf + ((size_t)(ct * 32 + lm)) * 64 + lk * 8;
        #pragma unroll
        for (int kc = 0; kc < 4; kc++) {
            short8 bf = *(const short8*)(wg + kc * 16);
            a = __builtin_amdgcn_mfma_f32_32x32x16_bf16(afr[kc], bf, a, 0, 0, 0);
        }
        float c2v = lc2[ct * 32 + lm];
        float* sb = scr[ct & 1];
        #pragma unroll
        for (int r = 0; r < 16; r++) {
            int tl = wv * 32 + (r & 3) + 8 * (r >> 2) + 4 * lk;
            sb[tl * 33 + lm] = c2v - 2.f * a[r];
        }
        __syncthreads();
        const float* sr = sb + tq * 33 + c0;
        #pragma unroll
        for (int j = 0; j < 16; j++) {
            float s = sr[j];
            if (s < best) { best = s; bidx = ct * 32 + c0 + j; }
        }
    }
    {
        float os = __shfl_xor(best, 1, 64);
        int   oi = __shfl_xor(bidx, 1, 64);
        if (os < best || (os == best && oi < bidx)) { best = os; bidx = oi; }
        if ((tid & 1) == 0) ibuf[tq] = bidx;
    }
    __syncthreads();
    float vql = 0.f;
    {
        int t = tid >> 1, dh = (tid & 1) * 32;
        int code = ibuf[t];
        const float4* cv = (const float4*)(cb + (size_t)code * 64 + dh);
        const float4* zv = (const float4*)(zrow + (size_t)t * 64 + dh);
        short* zqp = zq + ((size_t)(bb * T3 + t0 + t)) * 64 + dh;
        #pragma unroll
        for (int q = 0; q < 4; q++) {
            float4 c0v = cv[2 * q], c1v = cv[2 * q + 1];
            float4 z0 = zv[2 * q], z1 = zv[2 * q + 1];
            float d;
            d = z0.x - c0v.x; vql += d * d;
            d = z0.y - c0v.y; vql += d * d;
            d = z0.z - c0v.z; vql += d * d;
            d = z0.w - c0v.w; vql += d * d;
            d = z1.x - c1v.x; vql += d * d;
            d = z1.y - c1v.y; vql += d * d;
            d = z1.z - c1v.z; vql += d * d;
            d = z1.w - c1v.w; vql += d * d;
            short8 p;
            p[0] = f2bs(c0v.x); p[1] = f2bs(c0v.y); p[2] = f2bs(c0v.z); p[3] = f2bs(c0v.w);
            p[4] = f2bs(c1v.x); p[5] = f2bs(c1v.y); p[6] = f2bs(c1v.z); p[7] = f2bs(c1v.w);
            *(short8*)(zqp + q * 8) = p;
        }
    }
    {
        int d4 = (tid & 15) * 4;
        int g  = tid >> 4;
        float4 s4 = {0.f, 0.f, 0.f, 0.f};
        for (int t = g; t < 128; t += 16) {
            float4 v = *(const float4*)(cb + (size_t)ibuf[t] * 64 + d4);
            s4.x += v.x; s4.y += v.y; s4.z += v.z; s4.w += v.w;
        }
        *(float4*)(cscr + g * 64 + d4) = s4;
        __syncthreads();
        if (tid < 64) {
            float s = 0.f;
            #pragma unroll
            for (int g2 = 0; g2 < 16; g2++) s += cscr[g2 * 64 + tid];
            atomicAdd(cond + bb * 64 + tid, s);
        }
    }
    vql = block_sum256(vql);
    if (tid == 0) atomicAdd(acc, vql);
}

__global__ void fin_kernel(const float* __restrict__ cond,
                           const float* __restrict__ acc, float* __restrict__ out) {
    int i = threadIdx.x;   // 1024 threads
    out[i] = cond[i] * (1.f / (float)T3);
    if (i == 0) {
        float vq = acc[0] * (1.f / 4194304.f);   // B*D*T3
        out[1024] = vq;
        out[1025] = vq;
        out[1026] = acc[1] * (1.f / 4194304.f);  // B*C0*T0
    }
}

extern "C" void kernel_launch(void* const* d_in, const int* in_sizes, int n_in,
                              void* d_out, int out_size, void* d_ws, size_t ws_size,
                              hipStream_t stream) {
    const float* x   = (const float*)d_in[0];
    const float* w1  = (const float*)d_in[1];
    const float* b1  = (const float*)d_in[2];
    const float* w2  = (const float*)d_in[3];
    const float* b2  = (const float*)d_in[4];
    const float* w3  = (const float*)d_in[5];
    const float* b3  = (const float*)d_in[6];
    const float* cb  = (const float*)d_in[7];
    const float* dw1 = (const float*)d_in[8];
    const float* db1 = (const float*)d_in[9];
    const float* dw2 = (const float*)d_in[10];
    const float* db2 = (const float*)d_in[11];
    const float* dw3 = (const float*)d_in[12];
    const float* db3 = (const float*)d_in[13];
    float* out = (float*)d_out;

    char* ws = (char*)d_ws;
    short* a1   = (short*)(ws);                    // [16][16384][64] bf16; later r2
    short* a2   = (short*)(ws + 33554432);         // [16][8192][128] bf16; later r1
    float* ze   = (float*)(ws + 67108864);         // [16][4096][64] fp32
    short* zq   = (short*)(ws + 83886080);         // [16][4096][64] bf16
    short* wb2  = (short*)(ws + 92274688);
    short* wb3  = (short*)(ws + 92356608);
    short* wT1  = (short*)(ws + 92405760);
    short* wT2  = (short*)(ws + 92471296);
    short* cbbf = (short*)(ws + 92536832);         // [512][64] bf16
    short* w1b  = (short*)(ws + 92602368);         // [64][64] bf16 (im2col K)
    float* c2   = (float*)(ws + 92610560);
    float* cnd  = (float*)(ws + 92612608);
    float* acc  = (float*)(ws + 92616704);

    prep_kernel<<<160, 256, 0, stream>>>(cb, w1, w2, w3, dw1, dw2, c2, cnd, acc,
                                         wb2, wb3, wT1, wT2, cbbf, w1b);
    conv1_mfma<<<dim3(T1 / 128, 1, NB), 256, 0, stream>>>(x, w1b, b1, a1);
    conv_mfma_fwd<64, 128, 64, 5, 2, 128, 4, true, false>
        <<<dim3(T2 / 128, 2, NB), 256, 0, stream>>>(a1, wb2, b2, a2, T1, T2);
    conv_mfma_fwd<128, 64, 32, 3, 1, 64, 2, false, true>
        <<<dim3(T3 / 64, 2, NB), 128, 0, stream>>>(a2, wb3, b3, ze, T2, T3);
    quant_kernel<<<NB * (T3 / 128), 256, 0, stream>>>(ze, cb, cbbf, c2, zq, cnd, acc);
    conv_mfma_t<64, 128, 64, 128, 4, true>
        <<<dim3(T3 / 128, 2, NB), 256, 0, stream>>>(zq, wT1, db1, a2, T3);
    conv_mfma_t<128, 64, 32, 128, 4, true>
        <<<dim3(T2 / 128, 2, NB), 256, 0, stream>>>(a2, wT2, db2, a1, T2);
    convt3_loss<<<dim3(T1 / 256, 1, NB), 256, 0, stream>>>(a1, dw3, db3, x, acc);
    fin_kernel<<<1, 1024, 0, stream>>>(cnd, acc, out);
}